// Round 12
// baseline (2140.688 us; speedup 1.0000x reference)
//
#include <hip/hip_runtime.h>
#include <hip/hip_bf16.h>
#include <cstdint>
#include <cstddef>

#define CDIV(a,b) (((a)+(b)-1)/(b))

typedef __attribute__((ext_vector_type(8))) short vbf8;
typedef __attribute__((ext_vector_type(4))) float vf4;

__device__ inline unsigned short f2bf(float f) {
  unsigned u = __float_as_uint(f);
  unsigned r = (u + 0x7fffu + ((u >> 16) & 1u)) >> 16;
  return (unsigned short)r;
}
__device__ inline float bf2f(unsigned short h) { return __uint_as_float(((unsigned)h) << 16); }

// ============ encoder conv0: 1->256, 28->14, s2 p1, relu, ch-last hi/lo ========
__global__ __launch_bounds__(256) void conv_e0_cl_kernel(
    const float* __restrict__ x, const float* __restrict__ W,
    const float* __restrict__ b, unsigned short* __restrict__ hi,
    unsigned short* __restrict__ lo)
{
  __shared__ float s_img[784];
  const int n = blockIdx.x;
  const int co = threadIdx.x;
  for (int i = threadIdx.x; i < 784; i += 256) s_img[i] = x[(size_t)n*784 + i];
  float w[9];
#pragma unroll
  for (int t = 0; t < 9; ++t) w[t] = W[co*9 + t];
  const float bb = b[co];
  __syncthreads();
  for (int p = 0; p < 196; ++p) {
    int y = p / 14, xo = p % 14;
    float a = bb;
#pragma unroll
    for (int t = 0; t < 9; ++t) {
      int yi = 2*y + t/3 - 1, xi = 2*xo + t%3 - 1;
      if (yi >= 0 && yi < 28 && xi >= 0 && xi < 28) a = fmaf(w[t], s_img[yi*28 + xi], a);
    }
    a = fmaxf(a, 0.f);
    unsigned short h = f2bf(a);
    size_t oidx = ((size_t)n*196 + p)*256 + co;
    hi[oidx] = h;
    lo[oidx] = f2bf(a - bf2f(h));
  }
}

// ============ weight prep: 5 weights in one launch (blockIdx.y selects) ========
__global__ __launch_bounds__(256) void wprep5_kernel(
    const float* __restrict__ Wa, unsigned short* __restrict__ Ha, unsigned short* __restrict__ La,
    const float* __restrict__ Wb, unsigned short* __restrict__ Hb, unsigned short* __restrict__ Lb,
    const float* __restrict__ Wc, unsigned short* __restrict__ Hc, unsigned short* __restrict__ Lc,
    const float* __restrict__ Wd, unsigned short* __restrict__ Hd, unsigned short* __restrict__ Ld,
    const float* __restrict__ We, unsigned short* __restrict__ He, unsigned short* __restrict__ Le)
{
  int idx = blockIdx.x*256 + threadIdx.x;
  if (idx >= 589824) return;
  const float* W; unsigned short* Wh; unsigned short* Wl;
  switch (blockIdx.y) {
    case 0: W = Wa; Wh = Ha; Wl = La; break;
    case 1: W = Wb; Wh = Hb; Wl = Lb; break;
    case 2: W = Wc; Wh = Hc; Wl = Lc; break;
    case 3: W = Wd; Wh = Hd; Wl = Ld; break;
    default: W = We; Wh = He; Wl = Le; break;
  }
  int j   = idx & 7;
  int co  = (idx >> 3) & 255;
  int cig = (idx >> 11) & 31;
  int t   = idx >> 16;
  int ci  = cig*8 + j;
  float w = W[((size_t)co*256 + ci)*9 + t];
  unsigned short h = f2bf(w);
  Wh[idx] = h;
  Wl[idx] = f2bf(w - bf2f(h));
}

// ============ shared MFMA inner block ==========================================
template<int NFM, int WS, int CIG>
__device__ __forceinline__ void mfma_block(
    const vbf8* __restrict__ sbuf, const vbf8* __restrict__ wsrc, int cc,
    const int (&abase)[NFM], vf4 (&acc)[NFM][4], int cobase, int l15, int lq)
{
  constexpr int NKK = CIG/4;
#pragma unroll
  for (int t = 0; t < 9; ++t) {
    const int dy = t/3, dx = t%3;
#pragma unroll
    for (int kk = 0; kk < NKK; ++kk) {
      vbf8 bfr[4];
      const int cig_g = cc*CIG + kk*4 + lq;
#pragma unroll
      for (int nf = 0; nf < 4; ++nf)
        bfr[nf] = wsrc[((size_t)t*32 + cig_g)*256 + cobase + nf*16 + l15];
      vbf8 af[NFM];
      const int cigl = kk*4 + lq;
#pragma unroll
      for (int mf = 0; mf < NFM; ++mf) {
        int lin = abase[mf] + dy*WS + dx;
        af[mf] = sbuf[(lin*CIG + cigl) ^ (lin & 7)];
      }
#pragma unroll
      for (int mf = 0; mf < NFM; ++mf)
#pragma unroll
        for (int nf = 0; nf < 4; ++nf)
          acc[mf][nf] = __builtin_amdgcn_mfma_f32_16x16x32_bf16(af[mf], bfr[nf], acc[mf][nf], 0, 0, 0);
    }
  }
}

// ============ unified bf16 MFMA 3x3 conv, channel-last =========================
// DBUF=1: reg-prefetch double-buffer, 1 barrier/stage.
//   SPLIT stage schedule (8 stages, 12 MFMA passes): s0-3 stage A-hi(cc), run
//   Whi AND Wlo; s4-7 stage A-lo(cc), run Whi.  => hi*Whi + hi*Wlo + lo*Whi.
template<int STRIDE, int HO, int WO, int X0, int WOP, int ROWS, int HI, int WI,
         int PAD, int ACT, int SPLIT, int OUTMODE, int DBUF, int CIG>
__global__ __launch_bounds__(256, 2) void convmfma_kernel(
    const unsigned short* __restrict__ inT, const unsigned short* __restrict__ inTlo,
    const vbf8* __restrict__ Wt, const vbf8* __restrict__ Wtlo,
    const float* __restrict__ bias,
    unsigned short* __restrict__ outT, unsigned short* __restrict__ outTlo,
    float* __restrict__ outF)
{
  constexpr int NFM = ROWS*WOP/16;
  constexpr int RIN = (ROWS-1)*STRIDE + 3;
  constexpr int WS  = (WOP-1)*STRIDE + 3;
  constexpr int NCC = 256/(CIG*8);
  constexpr int NG  = SPLIT ? 3*NCC : NCC;      // 2-barrier path group count
  constexpr int NSTG = SPLIT ? 2*NCC : NCC;     // DBUF stage count (8 or 4)
  constexpr int NELEM = RIN*WS*CIG;
  constexpr int CEIL = (NELEM + 255) / 256;
  __shared__ vbf8 sA[DBUF ? 2 : 1][NELEM];

  const int n  = blockIdx.x;
  const int y0 = blockIdx.y * ROWS;
  const int tid = threadIdx.x;
  const int lane = tid & 63;
  const int wv = tid >> 6;
  const int l15 = lane & 15;
  const int lq  = lane >> 4;
  const int cobase = wv * 64;

  int abase[NFM];
#pragma unroll
  for (int mf = 0; mf < NFM; ++mf) {
    int pos = mf*16 + l15;
    abase[mf] = (pos / WOP) * STRIDE * WS + (pos % WOP) * STRIDE;
  }

  vf4 acc[NFM][4];
#pragma unroll
  for (int mf = 0; mf < NFM; ++mf)
#pragma unroll
    for (int nf = 0; nf < 4; ++nf) acc[mf][nf] = (vf4){0.f, 0.f, 0.f, 0.f};

  if constexpr (DBUF) {
    int goff[CEIL];
#pragma unroll
    for (int q = 0; q < CEIL; ++q) {
      int idx = tid + q*256;
      int lin = idx / CIG, cig = idx % CIG;
      int rr = lin / WS, xx = lin % WS;
      int yi = y0*STRIDE + rr - PAD, xi = X0*STRIDE + xx - PAD;
      bool ok = (idx < NELEM) && yi >= 0 && yi < HI && xi >= 0 && xi < WI;
      goff[q] = ok ? (int)((((size_t)n*HI + yi)*WI + xi)*256 + cig*8) : -1;
    }
    vbf8 r[CEIL];
    // prologue: stage 0 (hi plane, cc 0)
#pragma unroll
    for (int q = 0; q < CEIL; ++q) {
      vbf8 v = {0,0,0,0,0,0,0,0};
      if (goff[q] >= 0) v = *(const vbf8*)(inT + goff[q]);
      r[q] = v;
    }
#pragma unroll
    for (int q = 0; q < CEIL; ++q) {
      int idx = tid + q*256;
      if (idx < NELEM) { int lin = idx / CIG, cig = idx % CIG; sA[0][(lin*CIG + cig) ^ (lin & 7)] = r[q]; }
    }
    __syncthreads();
#pragma unroll 1
    for (int s = 0; s < NSTG; ++s) {
      if (s + 1 < NSTG) {
        const unsigned short* srcn = (SPLIT && (s+1) >= NCC) ? inTlo : inT;
        const int ccn = ((s+1) % NCC) * (CIG*8);
#pragma unroll
        for (int q = 0; q < CEIL; ++q) {
          vbf8 v = {0,0,0,0,0,0,0,0};
          if (goff[q] >= 0) v = *(const vbf8*)(srcn + goff[q] + ccn);
          r[q] = v;
        }
      }
      const int cc = s % NCC;
      mfma_block<NFM, WS, CIG>(sA[s & 1], Wt, cc, abase, acc, cobase, l15, lq);
      if (SPLIT && s < NCC)
        mfma_block<NFM, WS, CIG>(sA[s & 1], Wtlo, cc, abase, acc, cobase, l15, lq);
      if (s + 1 < NSTG) {
        vbf8* nb = sA[(s+1) & 1];
#pragma unroll
        for (int q = 0; q < CEIL; ++q) {
          int idx = tid + q*256;
          if (idx < NELEM) { int lin = idx / CIG, cig = idx % CIG; nb[(lin*CIG + cig) ^ (lin & 7)] = r[q]; }
        }
      }
      __syncthreads();
    }
  } else {
    // 2-barrier path: stage -> sync -> MFMA -> sync (12 groups when SPLIT)
#pragma unroll 1
    for (int g = 0; g < NG; ++g) {
      const int pass = g / NCC;
      const int cc = g % NCC;
      const unsigned short* src = (SPLIT && pass == 2) ? inTlo : inT;
      const vbf8* wsrc = (SPLIT && pass == 1) ? Wtlo : Wt;
      for (int idx = tid; idx < NELEM; idx += 256) {
        int lin = idx / CIG, cig = idx % CIG;
        int rr = lin / WS, xx = lin % WS;
        int yi = y0*STRIDE + rr - PAD, xi = X0*STRIDE + xx - PAD;
        vbf8 v = {0,0,0,0,0,0,0,0};
        if (yi >= 0 && yi < HI && xi >= 0 && xi < WI)
          v = *(const vbf8*)(src + ((((size_t)n*HI + yi)*WI + xi)*256 + cc*(CIG*8) + cig*8));
        sA[0][(lin*CIG + cig) ^ (lin & 7)] = v;
      }
      __syncthreads();
      mfma_block<NFM, WS, CIG>(sA[0], wsrc, cc, abase, acc, cobase, l15, lq);
      __syncthreads();
    }
  }

  float bb[4];
#pragma unroll
  for (int nf = 0; nf < 4; ++nf) bb[nf] = bias[cobase + nf*16 + l15];
#pragma unroll
  for (int mf = 0; mf < NFM; ++mf) {
#pragma unroll
    for (int q = 0; q < 4; ++q) {
      int pos = mf*16 + lq*4 + q;
      int y = y0 + pos/WOP, x = X0 + pos % WOP;
      if (X0 + WOP > WO && x >= WO) continue;
      if (HO % ROWS != 0 && y >= HO) continue;
#pragma unroll
      for (int nf = 0; nf < 4; ++nf) {
        float v = acc[mf][nf][q] + bb[nf];
        if (ACT) v = fmaxf(v, 0.f);
        const int co = cobase + nf*16 + l15;
        if (OUTMODE == 2) {
          outF[((size_t)n*256 + co)*(HO*WO) + y*WO + x] = v;
        } else {
          size_t oidx = (((size_t)n*HO + y)*WO + x)*256 + co;
          unsigned short h = f2bf(v);
          outT[oidx] = h;
          if (OUTMODE == 1) outTlo[oidx] = f2bf(v - bf2f(h));
        }
      }
    }
  }
}

// ============ bilinear x2 upsample, channel-last bf16 ==========================
template<int H, int W>
__global__ __launch_bounds__(256) void upsample_cl_kernel(
    const unsigned short* __restrict__ in, unsigned short* __restrict__ out, int nimg)
{
  constexpr int Ho = 2*H, Wo = 2*W;
  int idx = blockIdx.x*256 + threadIdx.x;
  int total = nimg * Ho * Wo * 32;
  if (idx >= total) return;
  int cig = idx & 31; int rest = idx >> 5;
  int xo = rest % Wo; rest /= Wo;
  int yo = rest % Ho; int n = rest / Ho;
  float ys = (float)(yo*(H-1)) / (float)(Ho-1);
  float xs = (float)(xo*(W-1)) / (float)(Wo-1);
  int ya = (int)ys; int yb = (ya+1 < H) ? ya+1 : H-1;
  int xa = (int)xs; int xb = (xa+1 < W) ? xa+1 : W-1;
  float wy = ys - (float)ya, wx = xs - (float)xa;
  const unsigned short* base = in + (size_t)n*H*W*256 + cig*8;
  vbf8 vaa = *(const vbf8*)(base + ((size_t)ya*W + xa)*256);
  vbf8 vab = *(const vbf8*)(base + ((size_t)ya*W + xb)*256);
  vbf8 vba = *(const vbf8*)(base + ((size_t)yb*W + xa)*256);
  vbf8 vbb = *(const vbf8*)(base + ((size_t)yb*W + xb)*256);
  vbf8 o;
#pragma unroll
  for (int j = 0; j < 8; ++j) {
    float r0 = bf2f((unsigned short)vaa[j])*(1.f-wy) + bf2f((unsigned short)vba[j])*wy;
    float r1 = bf2f((unsigned short)vab[j])*(1.f-wy) + bf2f((unsigned short)vbb[j])*wy;
    o[j] = (short)f2bf(r0*(1.f-wx) + r1*wx);
  }
  *(vbf8*)(out + (((size_t)n*Ho + yo)*Wo + xo)*256 + cig*8) = o;
}

// ============ output conv: 256->1, 3x3 pad1, sigmoid (channel-last) ============
__global__ __launch_bounds__(256) void conv_out_t_kernel(
    const unsigned short* __restrict__ a2t, const float* __restrict__ Wo,
    const float* __restrict__ bo, float* __restrict__ out)
{
  const int n = blockIdx.x;
  const int y0 = blockIdx.y * 7;
  const int tid = threadIdx.x;
  __shared__ vbf8 s_in[9*30*8];
  __shared__ float s_w[9*64];
  const int p = tid;
  const int y = p / 28, x = p % 28;
  float acc = 0.f;
  for (int cc = 0; cc < 4; ++cc) {
    for (int idx = tid; idx < 9*30*8; idx += 256) {
      int lin = idx >> 3, cig = idx & 7;
      int r = lin / 30, xx = lin % 30;
      int yi = y0 + r - 1, xi = xx - 1;
      vbf8 v = {0,0,0,0,0,0,0,0};
      if (yi >= 0 && yi < 28 && xi >= 0 && xi < 28)
        v = *(const vbf8*)(a2t + (((size_t)n*28 + yi)*28 + xi)*256 + cc*64 + cig*8);
      s_in[(lin*8 + cig) ^ (lin & 7)] = v;
    }
    for (int idx = tid; idx < 576; idx += 256) {
      int t = idx / 64, cil = idx % 64;
      s_w[t*64 + cil] = Wo[((size_t)cc*64 + cil)*9 + t];
    }
    __syncthreads();
    if (p < 196) {
      float a = acc;
#pragma unroll
      for (int t = 0; t < 9; ++t) {
        int lin = (y + t/3)*30 + (x + t%3);
#pragma unroll
        for (int cig = 0; cig < 8; ++cig) {
          vbf8 v = s_in[(lin*8 + cig) ^ (lin & 7)];
#pragma unroll
          for (int j = 0; j < 8; ++j)
            a = fmaf(bf2f((unsigned short)v[j]), s_w[t*64 + cig*8 + j], a);
        }
      }
      acc = a;
    }
    __syncthreads();
  }
  if (p < 196)
    out[(size_t)n*784 + (y0 + y)*28 + x] = 1.f/(1.f + expf(-(acc + bo[0])));
}

// ============ VQ: E prep — one pass: Et bf16 transpose + fp32 norms ============
__global__ __launch_bounds__(256) void eprep_kernel(
    const float* __restrict__ E, unsigned short* __restrict__ Et,
    float* __restrict__ norms)
{
  const int cb = blockIdx.x;          // 256 blocks
  const int tid = threadIdx.x;
  const int cl = tid >> 2;
  const int seg = tid & 3;
  const int code = cb*64 + cl;
  const float4* srcRow = (const float4*)(E + (size_t)code*4096);
  vbf8* dst = (vbf8*)Et;
  float nacc = 0.f;
#pragma unroll 4
  for (int g8 = 0; g8 < 128; ++g8) {
    const int kg = g8*4 + seg;        // vbf8-group index, 0..511
    float4 a = srcRow[kg*2], b = srcRow[kg*2 + 1];
    nacc += a.x*a.x + a.y*a.y + a.z*a.z + a.w*a.w
          + b.x*b.x + b.y*b.y + b.z*b.z + b.w*b.w;
    vbf8 v;
    v[0]=(short)f2bf(a.x); v[1]=(short)f2bf(a.y); v[2]=(short)f2bf(a.z); v[3]=(short)f2bf(a.w);
    v[4]=(short)f2bf(b.x); v[5]=(short)f2bf(b.y); v[6]=(short)f2bf(b.z); v[7]=(short)f2bf(b.w);
    dst[(size_t)kg*16384 + code] = v;
  }
  nacc += __shfl_xor(nacc, 1);
  nacc += __shfl_xor(nacc, 2);
  if (seg == 0) norms[code] = nacc;
}

// ============ VQ: stable counting-sort permutation by class ====================
__global__ __launch_bounds__(512) void perm_kernel(
    const int* __restrict__ c, int* __restrict__ perm, int* __restrict__ off)
{
  __shared__ int sc[512];
  __shared__ int cnt[8];
  __shared__ int base[9];
  const int i = threadIdx.x;
  sc[i] = c[i];
  if (i < 8) cnt[i] = 0;
  __syncthreads();
  atomicAdd(&cnt[sc[i]], 1);
  __syncthreads();
  if (i == 0) { int a = 0; for (int j = 0; j < 8; ++j) { base[j] = a; a += cnt[j]; } base[8] = a; }
  __syncthreads();
  const int ci = sc[i];
  int rank = 0;
  for (int j = 0; j < i; ++j) rank += (sc[j] == ci) ? 1 : 0;
  perm[base[ci] + rank] = i;
  if (i < 9) off[i] = base[i];
}

// ============ VQ: coarse bf16 MFMA distance GEMM ===============================
__global__ __launch_bounds__(256) void vq_coarse_kernel(
    const float* __restrict__ zE, const vbf8* __restrict__ Etv,
    const float* __restrict__ norms, const int* __restrict__ perm,
    const int* __restrict__ offs, float* __restrict__ dco)
{
  const int cls = blockIdx.x;
  const int mb  = blockIdx.y;
  const int kb  = blockIdx.z;
  const int s0 = offs[cls];
  const int total = offs[cls+1] - s0;
  int nrows = total - mb*64;
  if (nrows <= 0) return;
  if (nrows > 64) nrows = 64;

  __shared__ vbf8 sA[64*8];
  __shared__ int srow_s[64];
  const int tid = threadIdx.x;
  if (tid < 64) srow_s[tid] = (tid < nrows) ? perm[s0 + mb*64 + tid] : -1;
  __syncthreads();

  const int lane = tid & 63;
  const int wv = tid >> 6;
  const int l15 = lane & 15;
  const int lq  = lane >> 4;

  const int myrow = tid >> 2;
  const int seg = tid & 3;
  const int srow_mine = srow_s[myrow];
  const float* zbase = (srow_mine >= 0) ? (zE + (size_t)srow_mine*4096 + seg*16) : nullptr;

  const int cbase = cls*2048 + kb*256 + wv*64;

  vf4 acc[4][4];
#pragma unroll
  for (int mf = 0; mf < 4; ++mf)
#pragma unroll
    for (int nf = 0; nf < 4; ++nf) acc[mf][nf] = (vf4){0.f, 0.f, 0.f, 0.f};

#pragma unroll 1
  for (int k0 = 0; k0 < 4096; k0 += 64) {
    {
      float4 v0, v1, v2, v3;
      if (zbase) {
        const float4* p = (const float4*)(zbase + k0);
        v0 = p[0]; v1 = p[1]; v2 = p[2]; v3 = p[3];
      } else {
        v0 = v1 = v2 = v3 = (float4){0.f, 0.f, 0.f, 0.f};
      }
      vbf8 a, b;
      a[0]=(short)f2bf(v0.x); a[1]=(short)f2bf(v0.y); a[2]=(short)f2bf(v0.z); a[3]=(short)f2bf(v0.w);
      a[4]=(short)f2bf(v1.x); a[5]=(short)f2bf(v1.y); a[6]=(short)f2bf(v1.z); a[7]=(short)f2bf(v1.w);
      b[0]=(short)f2bf(v2.x); b[1]=(short)f2bf(v2.y); b[2]=(short)f2bf(v2.z); b[3]=(short)f2bf(v2.w);
      b[4]=(short)f2bf(v3.x); b[5]=(short)f2bf(v3.y); b[6]=(short)f2bf(v3.z); b[7]=(short)f2bf(v3.w);
      int c0 = seg*2;
      sA[myrow*8 + (c0 ^ (myrow & 7))]       = a;
      sA[myrow*8 + ((c0 + 1) ^ (myrow & 7))] = b;
    }
    __syncthreads();
#pragma unroll
    for (int kb32 = 0; kb32 < 2; ++kb32) {
      vbf8 af[4], bf[4];
#pragma unroll
      for (int mf = 0; mf < 4; ++mf) {
        int row = mf*16 + l15;
        af[mf] = sA[row*8 + ((kb32*4 + lq) ^ (row & 7))];
      }
      const size_t kg = (size_t)((k0 >> 3) + kb32*4 + lq);
#pragma unroll
      for (int nf = 0; nf < 4; ++nf)
        bf[nf] = Etv[kg*16384 + cbase + nf*16 + l15];
#pragma unroll
      for (int mf = 0; mf < 4; ++mf)
#pragma unroll
        for (int nf = 0; nf < 4; ++nf)
          acc[mf][nf] = __builtin_amdgcn_mfma_f32_16x16x32_bf16(af[mf], bf[nf], acc[mf][nf], 0, 0, 0);
    }
    __syncthreads();
  }

  float nrm[4];
#pragma unroll
  for (int nf = 0; nf < 4; ++nf) nrm[nf] = norms[cbase + nf*16 + l15];
#pragma unroll
  for (int mf = 0; mf < 4; ++mf) {
#pragma unroll
    for (int q = 0; q < 4; ++q) {
      int slot = mf*16 + lq*4 + q;
      if (slot < nrows) {
        int s = srow_s[slot];
        float* drow = dco + (size_t)s*2048 + (kb*256 + wv*64);
#pragma unroll
        for (int nf = 0; nf < 4; ++nf)
          drow[nf*16 + l15] = nrm[nf] - 2.f*acc[mf][nf][q];
      }
    }
  }
}

// ============ VQ: candidate selection + exact fp64 rescore =====================
__global__ __launch_bounds__(256) void vq_select_kernel(
    const float* __restrict__ dco, const int* __restrict__ c,
    const float* __restrict__ zE, const float* __restrict__ E,
    int* __restrict__ codes)
{
  const int s = blockIdx.x;
  const int cls = c[s];
  const int tid = threadIdx.x;
  const float* drow = dco + (size_t)s*2048;

  float mn = 3.4e38f, mx = -3.4e38f;
  for (int j = tid; j < 2048; j += 256) {
    float d = drow[j];
    mn = fminf(mn, d); mx = fmaxf(mx, d);
  }
  __shared__ float smn[256], smx[256];
  smn[tid] = mn; smx[tid] = mx;
  __syncthreads();
  for (int o = 128; o > 0; o >>= 1) {
    if (tid < o) { smn[tid] = fminf(smn[tid], smn[tid+o]); smx[tid] = fmaxf(smx[tid], smx[tid+o]); }
    __syncthreads();
  }
  const float dmin = smn[0], dmax = smx[0];
  const float margin = 0.06f*(dmax - dmin) + 1e-6f*fabsf(dmin) + 1e-20f;

  __shared__ int cand[64];
  __shared__ int cnt_s;
  if (tid == 0) cnt_s = 0;
  __syncthreads();
  for (int j = tid; j < 2048; j += 256) {
    if (drow[j] <= dmin + margin) {
      int p = atomicAdd(&cnt_s, 1);
      if (p < 64) cand[p] = j;
    }
  }
  __syncthreads();
  const int cnt = (cnt_s < 64) ? cnt_s : 64;

  __shared__ double red[256];
  __shared__ double bestd_s;
  __shared__ int bestc_s;
  if (tid == 0) { bestd_s = 1.0e300; bestc_s = 0x7fffffff; }
  __syncthreads();
  const float* zrow = zE + (size_t)s*4096;
  for (int t = 0; t < cnt; ++t) {
    const int gcode = cls*2048 + cand[t];
    const float* erow = E + (size_t)gcode*4096;
    double p = 0.0;
    for (int e2 = tid; e2 < 4096; e2 += 256) {
      double ev = (double)erow[e2];
      double zv = (double)zrow[e2];
      p += ev*ev - 2.0*zv*ev;
    }
    red[tid] = p;
    __syncthreads();
    for (int o = 128; o > 0; o >>= 1) {
      if (tid < o) red[tid] += red[tid+o];
      __syncthreads();
    }
    if (tid == 0) {
      double d = red[0];
      if (d < bestd_s || (d == bestd_s && gcode < bestc_s)) { bestd_s = d; bestc_s = gcode; }
    }
    __syncthreads();
  }
  if (tid == 0) codes[s] = bestc_s;
}

// gather + upsample<4,4>: zq fp32 out, zqt bf16 ch-last, u0t bf16 8x8 bilinear
__global__ __launch_bounds__(256) void gather_up_kernel(
    const int* __restrict__ codes, const int* __restrict__ perm,
    const float* __restrict__ E, float* __restrict__ zq,
    unsigned short* __restrict__ zqt, unsigned short* __restrict__ u0t)
{
  const int i = blockIdx.x;
  const int s = perm[i];
  const int code = codes[s];
  __shared__ unsigned short s_z[16*256];   // [sp][ci] bf16, 8 KB
  const float4* src = (const float4*)(E + (size_t)code*4096);
  float4* dst = (float4*)(zq + (size_t)i*4096);
  for (int t = threadIdx.x; t < 1024; t += 256) {
    float4 v = src[t];
    dst[t] = v;
    int e0 = t*4;
    int ci = e0 >> 4, sp = e0 & 15;
    unsigned short* zp = zqt + ((size_t)i*16 + sp)*256 + ci;
    unsigned short h0 = f2bf(v.x), h1 = f2bf(v.y), h2 = f2bf(v.z), h3 = f2bf(v.w);
    zp[0]   = h0;  zp[256] = h1;  zp[512] = h2;  zp[768] = h3;
    s_z[(sp+0)*256 + ci] = h0;
    s_z[(sp+1)*256 + ci] = h1;
    s_z[(sp+2)*256 + ci] = h2;
    s_z[(sp+3)*256 + ci] = h3;
  }
  __syncthreads();
  // bilinear 4->8, align_corners: src = out*3/7
  for (int q = threadIdx.x; q < 2048; q += 256) {
    int cig = q & 31;
    int pos = q >> 5;
    int xo = pos & 7, yo = pos >> 3;
    float ys = (float)(yo*3) / 7.f;
    float xs = (float)(xo*3) / 7.f;
    int ya = (int)ys; int yb = (ya+1 < 4) ? ya+1 : 3;
    int xa = (int)xs; int xb = (xa+1 < 4) ? xa+1 : 3;
    float wy = ys - (float)ya, wx = xs - (float)xa;
    vbf8 vaa = *(const vbf8*)(s_z + (ya*4+xa)*256 + cig*8);
    vbf8 vab = *(const vbf8*)(s_z + (ya*4+xb)*256 + cig*8);
    vbf8 vba = *(const vbf8*)(s_z + (yb*4+xa)*256 + cig*8);
    vbf8 vbb = *(const vbf8*)(s_z + (yb*4+xb)*256 + cig*8);
    vbf8 o;
#pragma unroll
    for (int j = 0; j < 8; ++j) {
      float r0 = bf2f((unsigned short)vaa[j])*(1.f-wy) + bf2f((unsigned short)vba[j])*wy;
      float r1 = bf2f((unsigned short)vab[j])*(1.f-wy) + bf2f((unsigned short)vbb[j])*wy;
      o[j] = (short)f2bf(r0*(1.f-wx) + r1*wx);
    }
    *(vbf8*)(u0t + (((size_t)i*8 + yo)*8 + xo)*256 + cig*8) = o;
  }
}

// ============ driver ===========================================================
extern "C" void kernel_launch(void* const* d_in, const int* in_sizes, int n_in,
                              void* d_out, int out_size, void* d_ws, size_t ws_size,
                              hipStream_t stream) {
  const float* x   = (const float*)d_in[0];
  const float* We0 = (const float*)d_in[1];
  const float* be0 = (const float*)d_in[2];
  const float* We1 = (const float*)d_in[3];
  const float* be1 = (const float*)d_in[4];
  const float* We2 = (const float*)d_in[5];
  const float* be2 = (const float*)d_in[6];
  const float* E   = (const float*)d_in[7];
  const float* Wd0 = (const float*)d_in[8];
  const float* bd0 = (const float*)d_in[9];
  const float* Wd1 = (const float*)d_in[10];
  const float* bd1 = (const float*)d_in[11];
  const float* Wd2 = (const float*)d_in[12];
  const float* bd2 = (const float*)d_in[13];
  const float* Wo  = (const float*)d_in[14];
  const float* bo  = (const float*)d_in[15];
  const int*   c   = (const int*)d_in[16];

  float* out = (float*)d_out;
  float* z_e = out + (size_t)512*784;
  float* zq  = z_e + (size_t)512*4096;

  char* ws = (char*)d_ws;
  size_t off = 0;
  float* norms = (float*)(ws + off); off += 65536;
  int* codes = (int*)(ws + off); off += 2048;
  int* perm = (int*)(ws + off); off += 2048;
  int* offs = (int*)(ws + off); off += 256;
  float* dco = (float*)(ws + off); off += (size_t)512*2048*4;
  unsigned short* zqt = (unsigned short*)(ws + off); off += (size_t)512*16*256*2;
  unsigned short* Et = (unsigned short*)(ws + off); off += (size_t)512*16384*8*2;
  unsigned short* Wt0  = (unsigned short*)(ws + off); off += 1179648;
  unsigned short* Wt0l = (unsigned short*)(ws + off); off += 1179648;
  unsigned short* Wt1  = (unsigned short*)(ws + off); off += 1179648;
  unsigned short* Wt1l = (unsigned short*)(ws + off); off += 1179648;
  unsigned short* Wt2  = (unsigned short*)(ws + off); off += 1179648;
  unsigned short* Wt2l = (unsigned short*)(ws + off); off += 1179648;
  unsigned short* We1h = (unsigned short*)(ws + off); off += 1179648;
  unsigned short* We1l = (unsigned short*)(ws + off); off += 1179648;
  unsigned short* We2h = (unsigned short*)(ws + off); off += 1179648;
  unsigned short* We2l = (unsigned short*)(ws + off); off += 1179648;
  char* big = ws + off;
  size_t avail = (ws_size > off) ? ws_size - off : 0;

  int NB = 512;
  while (NB > 1 && (size_t)NB * 1350656ull > avail) NB >>= 1;
  const int nch = 512 / NB;

  size_t o = 0;
  unsigned short* h0h = (unsigned short*)(big + o); o += (size_t)NB*100352;
  unsigned short* h0l = (unsigned short*)(big + o); o += (size_t)NB*100352;
  unsigned short* h1h = (unsigned short*)(big + o); o += (size_t)NB*25088;
  unsigned short* h1l = (unsigned short*)(big + o); o += (size_t)NB*25088;
  unsigned short* u0t = (unsigned short*)(big + o); o += (size_t)NB*32768;
  unsigned short* a0t = (unsigned short*)(big + o); o += (size_t)NB*32768;
  unsigned short* u1t = (unsigned short*)(big + o); o += (size_t)NB*131072;
  unsigned short* a1t = (unsigned short*)(big + o); o += (size_t)NB*100352;
  unsigned short* u2t = (unsigned short*)(big + o); o += (size_t)NB*401408;
  unsigned short* a2t = (unsigned short*)(big + o); o += (size_t)NB*401408;

  // ---- weight prep (single fused launch) + codebook prep ----
  wprep5_kernel<<<dim3(CDIV(589824,256),5), 256, 0, stream>>>(
      Wd0, Wt0, Wt0l, Wd1, Wt1, Wt1l, Wd2, Wt2, Wt2l,
      We1, We1h, We1l, We2, We2h, We2l);
  eprep_kernel<<<256, 256, 0, stream>>>(E, Et, norms);

  // ---- encoder (bf16x3 split MFMA, 8-stage DBUF schedule, chunked) ----
  for (int ch = 0; ch < nch; ++ch) {
    conv_e0_cl_kernel<<<NB, 256, 0, stream>>>(x + (size_t)ch*NB*784, We0, be0, h0h, h0l);
    convmfma_kernel<2,7,7,0,8,8, 14,14,1,1,1,1, 1,8><<<dim3(NB,1), 256, 0, stream>>>(
        h0h, h0l, (const vbf8*)We1h, (const vbf8*)We1l, be1, h1h, h1l, nullptr);
    convmfma_kernel<2,4,4,0,4,4, 7,7,1,0,1,2, 1,8><<<dim3(NB,1), 256, 0, stream>>>(
        h1h, h1l, (const vbf8*)We2h, (const vbf8*)We2l, be2, nullptr, nullptr,
        z_e + (size_t)ch*NB*4096);
  }
  // ---- VQ: coarse MFMA + exact rescore ----
  perm_kernel<<<1, 512, 0, stream>>>(c, perm, offs);
  vq_coarse_kernel<<<dim3(8,8,8), 256, 0, stream>>>(
      z_e, (const vbf8*)Et, norms, perm, offs, dco);
  vq_select_kernel<<<512, 256, 0, stream>>>(dco, c, z_e, E, codes);
  gather_up_kernel<<<512, 256, 0, stream>>>(codes, perm, E, zq, zqt, u0t);

  // ---- decoder (bf16 MFMA, channel-last, chunked) ----
  for (int ch = 0; ch < nch; ++ch) {
    convmfma_kernel<1,8,8,0,8,8, 8,8,1,1,0,0, 1,8><<<dim3(NB,1), 256, 0, stream>>>(
        u0t + (size_t)ch*NB*16384, nullptr, (const vbf8*)Wt0, nullptr, bd0, a0t, nullptr, nullptr);
    upsample_cl_kernel<8,8><<<CDIV(NB*8192,256), 256, 0, stream>>>(a0t, u1t, NB);
    convmfma_kernel<1,14,14,0,16,4, 16,16,0,1,0,0, 1,8><<<dim3(NB,4), 256, 0, stream>>>(
        u1t, nullptr, (const vbf8*)Wt1, nullptr, bd1, a1t, nullptr, nullptr);
    upsample_cl_kernel<14,14><<<CDIV(NB*25088,256), 256, 0, stream>>>(a1t, u2t, NB);
    // d2: WOP=28, CIG=8, 2-barrier path — R7-proven 540 µs config
    convmfma_kernel<1,28,28,0,28,4, 28,28,1,1,0,0, 0,8><<<dim3(NB,7), 256, 0, stream>>>(
        u2t, nullptr, (const vbf8*)Wt2, nullptr, bd2, a2t, nullptr, nullptr);
    conv_out_t_kernel<<<dim3(NB,4), 256, 0, stream>>>(a2t, Wo, bo, out + (size_t)ch*NB*784);
  }
}

// Round 13
// 1847.894 us; speedup vs baseline: 1.1584x; 1.1584x over previous
//
#include <hip/hip_runtime.h>
#include <hip/hip_bf16.h>
#include <cstdint>
#include <cstddef>

#define CDIV(a,b) (((a)+(b)-1)/(b))

typedef __attribute__((ext_vector_type(8))) short vbf8;
typedef __attribute__((ext_vector_type(4))) float vf4;

__device__ inline unsigned short f2bf(float f) {
  unsigned u = __float_as_uint(f);
  unsigned r = (u + 0x7fffu + ((u >> 16) & 1u)) >> 16;
  return (unsigned short)r;
}
__device__ inline float bf2f(unsigned short h) { return __uint_as_float(((unsigned)h) << 16); }

// ============ encoder conv0: 1->256, 28->14, s2 p1, relu, ch-last hi/lo ========
__global__ __launch_bounds__(256) void conv_e0_cl_kernel(
    const float* __restrict__ x, const float* __restrict__ W,
    const float* __restrict__ b, unsigned short* __restrict__ hi,
    unsigned short* __restrict__ lo)
{
  __shared__ float s_img[784];
  const int n = blockIdx.x;
  const int co = threadIdx.x;
  for (int i = threadIdx.x; i < 784; i += 256) s_img[i] = x[(size_t)n*784 + i];
  float w[9];
#pragma unroll
  for (int t = 0; t < 9; ++t) w[t] = W[co*9 + t];
  const float bb = b[co];
  __syncthreads();
  for (int p = 0; p < 196; ++p) {
    int y = p / 14, xo = p % 14;
    float a = bb;
#pragma unroll
    for (int t = 0; t < 9; ++t) {
      int yi = 2*y + t/3 - 1, xi = 2*xo + t%3 - 1;
      if (yi >= 0 && yi < 28 && xi >= 0 && xi < 28) a = fmaf(w[t], s_img[yi*28 + xi], a);
    }
    a = fmaxf(a, 0.f);
    unsigned short h = f2bf(a);
    size_t oidx = ((size_t)n*196 + p)*256 + co;
    hi[oidx] = h;
    lo[oidx] = f2bf(a - bf2f(h));
  }
}

// ============ weight prep: 5 weights in one launch (blockIdx.y selects) ========
__global__ __launch_bounds__(256) void wprep5_kernel(
    const float* __restrict__ Wa, unsigned short* __restrict__ Ha, unsigned short* __restrict__ La,
    const float* __restrict__ Wb, unsigned short* __restrict__ Hb, unsigned short* __restrict__ Lb,
    const float* __restrict__ Wc, unsigned short* __restrict__ Hc, unsigned short* __restrict__ Lc,
    const float* __restrict__ Wd, unsigned short* __restrict__ Hd, unsigned short* __restrict__ Ld,
    const float* __restrict__ We, unsigned short* __restrict__ He, unsigned short* __restrict__ Le)
{
  int idx = blockIdx.x*256 + threadIdx.x;
  if (idx >= 589824) return;
  const float* W; unsigned short* Wh; unsigned short* Wl;
  switch (blockIdx.y) {
    case 0: W = Wa; Wh = Ha; Wl = La; break;
    case 1: W = Wb; Wh = Hb; Wl = Lb; break;
    case 2: W = Wc; Wh = Hc; Wl = Lc; break;
    case 3: W = Wd; Wh = Hd; Wl = Ld; break;
    default: W = We; Wh = He; Wl = Le; break;
  }
  int j   = idx & 7;
  int co  = (idx >> 3) & 255;
  int cig = (idx >> 11) & 31;
  int t   = idx >> 16;
  int ci  = cig*8 + j;
  float w = W[((size_t)co*256 + ci)*9 + t];
  unsigned short h = f2bf(w);
  Wh[idx] = h;
  Wl[idx] = f2bf(w - bf2f(h));
}

// ============ shared MFMA inner block ==========================================
template<int NFM, int WS, int CIG>
__device__ __forceinline__ void mfma_block(
    const vbf8* __restrict__ sbuf, const vbf8* __restrict__ wsrc, int cc,
    const int (&abase)[NFM], vf4 (&acc)[NFM][4], int cobase, int l15, int lq)
{
  constexpr int NKK = CIG/4;
#pragma unroll
  for (int t = 0; t < 9; ++t) {
    const int dy = t/3, dx = t%3;
#pragma unroll
    for (int kk = 0; kk < NKK; ++kk) {
      vbf8 bfr[4];
      const int cig_g = cc*CIG + kk*4 + lq;
#pragma unroll
      for (int nf = 0; nf < 4; ++nf)
        bfr[nf] = wsrc[((size_t)t*32 + cig_g)*256 + cobase + nf*16 + l15];
      vbf8 af[NFM];
      const int cigl = kk*4 + lq;
#pragma unroll
      for (int mf = 0; mf < NFM; ++mf) {
        int lin = abase[mf] + dy*WS + dx;
        af[mf] = sbuf[(lin*CIG + cigl) ^ (lin & 7)];
      }
#pragma unroll
      for (int mf = 0; mf < NFM; ++mf)
#pragma unroll
        for (int nf = 0; nf < 4; ++nf)
          acc[mf][nf] = __builtin_amdgcn_mfma_f32_16x16x32_bf16(af[mf], bfr[nf], acc[mf][nf], 0, 0, 0);
    }
  }
}

// ============ unified bf16 MFMA 3x3 conv, channel-last =========================
// DBUF=1: reg-prefetch double-buffer, 1 barrier/stage.
//   SPLIT DBUF schedule (8 stages): s0-3 stage A-hi(cc): MFMA Whi, THEN issue
//   prefetch (sched_barrier-pinned, live across ONE block only), MFMA Wlo.
//   s4-7 stage A-lo(cc): prefetch-issue then MFMA Whi (R10 pattern).
//   => hi*Whi + hi*Wlo + lo*Whi, 8 stagings instead of 12.
template<int STRIDE, int HO, int WO, int X0, int WOP, int ROWS, int HI, int WI,
         int PAD, int ACT, int SPLIT, int OUTMODE, int DBUF, int CIG>
__global__ __launch_bounds__(256, 2) void convmfma_kernel(
    const unsigned short* __restrict__ inT, const unsigned short* __restrict__ inTlo,
    const vbf8* __restrict__ Wt, const vbf8* __restrict__ Wtlo,
    const float* __restrict__ bias,
    unsigned short* __restrict__ outT, unsigned short* __restrict__ outTlo,
    float* __restrict__ outF)
{
  constexpr int NFM = ROWS*WOP/16;
  constexpr int RIN = (ROWS-1)*STRIDE + 3;
  constexpr int WS  = (WOP-1)*STRIDE + 3;
  constexpr int NCC = 256/(CIG*8);
  constexpr int NG  = SPLIT ? 3*NCC : NCC;      // 2-barrier path group count
  constexpr int NSTG = SPLIT ? 2*NCC : NCC;     // DBUF stage count
  constexpr int NELEM = RIN*WS*CIG;
  constexpr int CEIL = (NELEM + 255) / 256;
  __shared__ vbf8 sA[DBUF ? 2 : 1][NELEM];

  const int n  = blockIdx.x;
  const int y0 = blockIdx.y * ROWS;
  const int tid = threadIdx.x;
  const int lane = tid & 63;
  const int wv = tid >> 6;
  const int l15 = lane & 15;
  const int lq  = lane >> 4;
  const int cobase = wv * 64;

  int abase[NFM];
#pragma unroll
  for (int mf = 0; mf < NFM; ++mf) {
    int pos = mf*16 + l15;
    abase[mf] = (pos / WOP) * STRIDE * WS + (pos % WOP) * STRIDE;
  }

  vf4 acc[NFM][4];
#pragma unroll
  for (int mf = 0; mf < NFM; ++mf)
#pragma unroll
    for (int nf = 0; nf < 4; ++nf) acc[mf][nf] = (vf4){0.f, 0.f, 0.f, 0.f};

  if constexpr (DBUF) {
    int goff[CEIL];
#pragma unroll
    for (int q = 0; q < CEIL; ++q) {
      int idx = tid + q*256;
      int lin = idx / CIG, cig = idx % CIG;
      int rr = lin / WS, xx = lin % WS;
      int yi = y0*STRIDE + rr - PAD, xi = X0*STRIDE + xx - PAD;
      bool ok = (idx < NELEM) && yi >= 0 && yi < HI && xi >= 0 && xi < WI;
      goff[q] = ok ? (int)((((size_t)n*HI + yi)*WI + xi)*256 + cig*8) : -1;
    }
    vbf8 r[CEIL];
    // prologue: stage 0 (hi plane, cc 0)
#pragma unroll
    for (int q = 0; q < CEIL; ++q) {
      vbf8 v = {0,0,0,0,0,0,0,0};
      if (goff[q] >= 0) v = *(const vbf8*)(inT + goff[q]);
      r[q] = v;
    }
#pragma unroll
    for (int q = 0; q < CEIL; ++q) {
      int idx = tid + q*256;
      if (idx < NELEM) { int lin = idx / CIG, cig = idx % CIG; sA[0][(lin*CIG + cig) ^ (lin & 7)] = r[q]; }
    }
    __syncthreads();
#pragma unroll 1
    for (int s = 0; s < NSTG; ++s) {
      const int cc = s % NCC;
      const bool isHi = SPLIT && (s < NCC);
      const unsigned short* srcn = (SPLIT && (s+1) >= NCC) ? inTlo : inT;
      const int ccn = ((s+1) % NCC) * (CIG*8);
      if (isHi) {
        // pass 1: hi * Whi
        mfma_block<NFM, WS, CIG>(sA[s & 1], Wt, cc, abase, acc, cobase, l15, lq);
        __builtin_amdgcn_sched_barrier(0);   // pin: prefetch not hoisted above pass 1
        if (s + 1 < NSTG) {
#pragma unroll
          for (int q = 0; q < CEIL; ++q) {
            vbf8 v = {0,0,0,0,0,0,0,0};
            if (goff[q] >= 0) v = *(const vbf8*)(srcn + goff[q] + ccn);
            r[q] = v;
          }
        }
        // pass 2: hi * Wlo (prefetch latency hides under this block)
        mfma_block<NFM, WS, CIG>(sA[s & 1], Wtlo, cc, abase, acc, cobase, l15, lq);
      } else {
        if (s + 1 < NSTG) {
#pragma unroll
          for (int q = 0; q < CEIL; ++q) {
            vbf8 v = {0,0,0,0,0,0,0,0};
            if (goff[q] >= 0) v = *(const vbf8*)(srcn + goff[q] + ccn);
            r[q] = v;
          }
        }
        mfma_block<NFM, WS, CIG>(sA[s & 1], Wt, cc, abase, acc, cobase, l15, lq);
      }
      if (s + 1 < NSTG) {
        vbf8* nb = sA[(s+1) & 1];
#pragma unroll
        for (int q = 0; q < CEIL; ++q) {
          int idx = tid + q*256;
          if (idx < NELEM) { int lin = idx / CIG, cig = idx % CIG; nb[(lin*CIG + cig) ^ (lin & 7)] = r[q]; }
        }
      }
      __syncthreads();
    }
  } else {
    // 2-barrier path: stage -> sync -> MFMA -> sync (12 groups when SPLIT)
#pragma unroll 1
    for (int g = 0; g < NG; ++g) {
      const int pass = g / NCC;
      const int cc = g % NCC;
      const unsigned short* src = (SPLIT && pass == 2) ? inTlo : inT;
      const vbf8* wsrc = (SPLIT && pass == 1) ? Wtlo : Wt;
      for (int idx = tid; idx < NELEM; idx += 256) {
        int lin = idx / CIG, cig = idx % CIG;
        int rr = lin / WS, xx = lin % WS;
        int yi = y0*STRIDE + rr - PAD, xi = X0*STRIDE + xx - PAD;
        vbf8 v = {0,0,0,0,0,0,0,0};
        if (yi >= 0 && yi < HI && xi >= 0 && xi < WI)
          v = *(const vbf8*)(src + ((((size_t)n*HI + yi)*WI + xi)*256 + cc*(CIG*8) + cig*8));
        sA[0][(lin*CIG + cig) ^ (lin & 7)] = v;
      }
      __syncthreads();
      mfma_block<NFM, WS, CIG>(sA[0], wsrc, cc, abase, acc, cobase, l15, lq);
      __syncthreads();
    }
  }

  float bb[4];
#pragma unroll
  for (int nf = 0; nf < 4; ++nf) bb[nf] = bias[cobase + nf*16 + l15];
#pragma unroll
  for (int mf = 0; mf < NFM; ++mf) {
#pragma unroll
    for (int q = 0; q < 4; ++q) {
      int pos = mf*16 + lq*4 + q;
      int y = y0 + pos/WOP, x = X0 + pos % WOP;
      if (X0 + WOP > WO && x >= WO) continue;
      if (HO % ROWS != 0 && y >= HO) continue;
#pragma unroll
      for (int nf = 0; nf < 4; ++nf) {
        float v = acc[mf][nf][q] + bb[nf];
        if (ACT) v = fmaxf(v, 0.f);
        const int co = cobase + nf*16 + l15;
        if (OUTMODE == 2) {
          outF[((size_t)n*256 + co)*(HO*WO) + y*WO + x] = v;
        } else {
          size_t oidx = (((size_t)n*HO + y)*WO + x)*256 + co;
          unsigned short h = f2bf(v);
          outT[oidx] = h;
          if (OUTMODE == 1) outTlo[oidx] = f2bf(v - bf2f(h));
        }
      }
    }
  }
}

// ============ bilinear x2 upsample, channel-last bf16 ==========================
template<int H, int W>
__global__ __launch_bounds__(256) void upsample_cl_kernel(
    const unsigned short* __restrict__ in, unsigned short* __restrict__ out, int nimg)
{
  constexpr int Ho = 2*H, Wo = 2*W;
  int idx = blockIdx.x*256 + threadIdx.x;
  int total = nimg * Ho * Wo * 32;
  if (idx >= total) return;
  int cig = idx & 31; int rest = idx >> 5;
  int xo = rest % Wo; rest /= Wo;
  int yo = rest % Ho; int n = rest / Ho;
  float ys = (float)(yo*(H-1)) / (float)(Ho-1);
  float xs = (float)(xo*(W-1)) / (float)(Wo-1);
  int ya = (int)ys; int yb = (ya+1 < H) ? ya+1 : H-1;
  int xa = (int)xs; int xb = (xa+1 < W) ? xa+1 : W-1;
  float wy = ys - (float)ya, wx = xs - (float)xa;
  const unsigned short* base = in + (size_t)n*H*W*256 + cig*8;
  vbf8 vaa = *(const vbf8*)(base + ((size_t)ya*W + xa)*256);
  vbf8 vab = *(const vbf8*)(base + ((size_t)ya*W + xb)*256);
  vbf8 vba = *(const vbf8*)(base + ((size_t)yb*W + xa)*256);
  vbf8 vbb = *(const vbf8*)(base + ((size_t)yb*W + xb)*256);
  vbf8 o;
#pragma unroll
  for (int j = 0; j < 8; ++j) {
    float r0 = bf2f((unsigned short)vaa[j])*(1.f-wy) + bf2f((unsigned short)vba[j])*wy;
    float r1 = bf2f((unsigned short)vab[j])*(1.f-wy) + bf2f((unsigned short)vbb[j])*wy;
    o[j] = (short)f2bf(r0*(1.f-wx) + r1*wx);
  }
  *(vbf8*)(out + (((size_t)n*Ho + yo)*Wo + xo)*256 + cig*8) = o;
}

// ============ output conv: 256->1, 3x3 pad1, sigmoid (channel-last) ============
__global__ __launch_bounds__(256) void conv_out_t_kernel(
    const unsigned short* __restrict__ a2t, const float* __restrict__ Wo,
    const float* __restrict__ bo, float* __restrict__ out)
{
  const int n = blockIdx.x;
  const int y0 = blockIdx.y * 7;
  const int tid = threadIdx.x;
  __shared__ vbf8 s_in[9*30*8];
  __shared__ float s_w[9*64];
  const int p = tid;
  const int y = p / 28, x = p % 28;
  float acc = 0.f;
  for (int cc = 0; cc < 4; ++cc) {
    for (int idx = tid; idx < 9*30*8; idx += 256) {
      int lin = idx >> 3, cig = idx & 7;
      int r = lin / 30, xx = lin % 30;
      int yi = y0 + r - 1, xi = xx - 1;
      vbf8 v = {0,0,0,0,0,0,0,0};
      if (yi >= 0 && yi < 28 && xi >= 0 && xi < 28)
        v = *(const vbf8*)(a2t + (((size_t)n*28 + yi)*28 + xi)*256 + cc*64 + cig*8);
      s_in[(lin*8 + cig) ^ (lin & 7)] = v;
    }
    for (int idx = tid; idx < 576; idx += 256) {
      int t = idx / 64, cil = idx % 64;
      s_w[t*64 + cil] = Wo[((size_t)cc*64 + cil)*9 + t];
    }
    __syncthreads();
    if (p < 196) {
      float a = acc;
#pragma unroll
      for (int t = 0; t < 9; ++t) {
        int lin = (y + t/3)*30 + (x + t%3);
#pragma unroll
        for (int cig = 0; cig < 8; ++cig) {
          vbf8 v = s_in[(lin*8 + cig) ^ (lin & 7)];
#pragma unroll
          for (int j = 0; j < 8; ++j)
            a = fmaf(bf2f((unsigned short)v[j]), s_w[t*64 + cig*8 + j], a);
        }
      }
      acc = a;
    }
    __syncthreads();
  }
  if (p < 196)
    out[(size_t)n*784 + (y0 + y)*28 + x] = 1.f/(1.f + expf(-(acc + bo[0])));
}

// ============ VQ: E prep — one pass: Et bf16 transpose + fp32 norms ============
__global__ __launch_bounds__(256) void eprep_kernel(
    const float* __restrict__ E, unsigned short* __restrict__ Et,
    float* __restrict__ norms)
{
  const int cb = blockIdx.x;          // 256 blocks
  const int tid = threadIdx.x;
  const int cl = tid >> 2;
  const int seg = tid & 3;
  const int code = cb*64 + cl;
  const float4* srcRow = (const float4*)(E + (size_t)code*4096);
  vbf8* dst = (vbf8*)Et;
  float nacc = 0.f;
#pragma unroll 4
  for (int g8 = 0; g8 < 128; ++g8) {
    const int kg = g8*4 + seg;        // vbf8-group index, 0..511
    float4 a = srcRow[kg*2], b = srcRow[kg*2 + 1];
    nacc += a.x*a.x + a.y*a.y + a.z*a.z + a.w*a.w
          + b.x*b.x + b.y*b.y + b.z*b.z + b.w*b.w;
    vbf8 v;
    v[0]=(short)f2bf(a.x); v[1]=(short)f2bf(a.y); v[2]=(short)f2bf(a.z); v[3]=(short)f2bf(a.w);
    v[4]=(short)f2bf(b.x); v[5]=(short)f2bf(b.y); v[6]=(short)f2bf(b.z); v[7]=(short)f2bf(b.w);
    dst[(size_t)kg*16384 + code] = v;
  }
  nacc += __shfl_xor(nacc, 1);
  nacc += __shfl_xor(nacc, 2);
  if (seg == 0) norms[code] = nacc;
}

// ============ VQ: stable counting-sort permutation by class ====================
__global__ __launch_bounds__(512) void perm_kernel(
    const int* __restrict__ c, int* __restrict__ perm, int* __restrict__ off)
{
  __shared__ int sc[512];
  __shared__ int cnt[8];
  __shared__ int base[9];
  const int i = threadIdx.x;
  sc[i] = c[i];
  if (i < 8) cnt[i] = 0;
  __syncthreads();
  atomicAdd(&cnt[sc[i]], 1);
  __syncthreads();
  if (i == 0) { int a = 0; for (int j = 0; j < 8; ++j) { base[j] = a; a += cnt[j]; } base[8] = a; }
  __syncthreads();
  const int ci = sc[i];
  int rank = 0;
  for (int j = 0; j < i; ++j) rank += (sc[j] == ci) ? 1 : 0;
  perm[base[ci] + rank] = i;
  if (i < 9) off[i] = base[i];
}

// ============ VQ: coarse bf16 MFMA distance GEMM ===============================
__global__ __launch_bounds__(256) void vq_coarse_kernel(
    const float* __restrict__ zE, const vbf8* __restrict__ Etv,
    const float* __restrict__ norms, const int* __restrict__ perm,
    const int* __restrict__ offs, float* __restrict__ dco)
{
  const int cls = blockIdx.x;
  const int mb  = blockIdx.y;
  const int kb  = blockIdx.z;
  const int s0 = offs[cls];
  const int total = offs[cls+1] - s0;
  int nrows = total - mb*64;
  if (nrows <= 0) return;
  if (nrows > 64) nrows = 64;

  __shared__ vbf8 sA[64*8];
  __shared__ int srow_s[64];
  const int tid = threadIdx.x;
  if (tid < 64) srow_s[tid] = (tid < nrows) ? perm[s0 + mb*64 + tid] : -1;
  __syncthreads();

  const int lane = tid & 63;
  const int wv = tid >> 6;
  const int l15 = lane & 15;
  const int lq  = lane >> 4;

  const int myrow = tid >> 2;
  const int seg = tid & 3;
  const int srow_mine = srow_s[myrow];
  const float* zbase = (srow_mine >= 0) ? (zE + (size_t)srow_mine*4096 + seg*16) : nullptr;

  const int cbase = cls*2048 + kb*256 + wv*64;

  vf4 acc[4][4];
#pragma unroll
  for (int mf = 0; mf < 4; ++mf)
#pragma unroll
    for (int nf = 0; nf < 4; ++nf) acc[mf][nf] = (vf4){0.f, 0.f, 0.f, 0.f};

#pragma unroll 1
  for (int k0 = 0; k0 < 4096; k0 += 64) {
    {
      float4 v0, v1, v2, v3;
      if (zbase) {
        const float4* p = (const float4*)(zbase + k0);
        v0 = p[0]; v1 = p[1]; v2 = p[2]; v3 = p[3];
      } else {
        v0 = v1 = v2 = v3 = (float4){0.f, 0.f, 0.f, 0.f};
      }
      vbf8 a, b;
      a[0]=(short)f2bf(v0.x); a[1]=(short)f2bf(v0.y); a[2]=(short)f2bf(v0.z); a[3]=(short)f2bf(v0.w);
      a[4]=(short)f2bf(v1.x); a[5]=(short)f2bf(v1.y); a[6]=(short)f2bf(v1.z); a[7]=(short)f2bf(v1.w);
      b[0]=(short)f2bf(v2.x); b[1]=(short)f2bf(v2.y); b[2]=(short)f2bf(v2.z); b[3]=(short)f2bf(v2.w);
      b[4]=(short)f2bf(v3.x); b[5]=(short)f2bf(v3.y); b[6]=(short)f2bf(v3.z); b[7]=(short)f2bf(v3.w);
      int c0 = seg*2;
      sA[myrow*8 + (c0 ^ (myrow & 7))]       = a;
      sA[myrow*8 + ((c0 + 1) ^ (myrow & 7))] = b;
    }
    __syncthreads();
#pragma unroll
    for (int kb32 = 0; kb32 < 2; ++kb32) {
      vbf8 af[4], bf[4];
#pragma unroll
      for (int mf = 0; mf < 4; ++mf) {
        int row = mf*16 + l15;
        af[mf] = sA[row*8 + ((kb32*4 + lq) ^ (row & 7))];
      }
      const size_t kg = (size_t)((k0 >> 3) + kb32*4 + lq);
#pragma unroll
      for (int nf = 0; nf < 4; ++nf)
        bf[nf] = Etv[kg*16384 + cbase + nf*16 + l15];
#pragma unroll
      for (int mf = 0; mf < 4; ++mf)
#pragma unroll
        for (int nf = 0; nf < 4; ++nf)
          acc[mf][nf] = __builtin_amdgcn_mfma_f32_16x16x32_bf16(af[mf], bf[nf], acc[mf][nf], 0, 0, 0);
    }
    __syncthreads();
  }

  float nrm[4];
#pragma unroll
  for (int nf = 0; nf < 4; ++nf) nrm[nf] = norms[cbase + nf*16 + l15];
#pragma unroll
  for (int mf = 0; mf < 4; ++mf) {
#pragma unroll
    for (int q = 0; q < 4; ++q) {
      int slot = mf*16 + lq*4 + q;
      if (slot < nrows) {
        int s = srow_s[slot];
        float* drow = dco + (size_t)s*2048 + (kb*256 + wv*64);
#pragma unroll
        for (int nf = 0; nf < 4; ++nf)
          drow[nf*16 + l15] = nrm[nf] - 2.f*acc[mf][nf][q];
      }
    }
  }
}

// ============ VQ: candidate selection + exact fp64 rescore =====================
__global__ __launch_bounds__(256) void vq_select_kernel(
    const float* __restrict__ dco, const int* __restrict__ c,
    const float* __restrict__ zE, const float* __restrict__ E,
    int* __restrict__ codes)
{
  const int s = blockIdx.x;
  const int cls = c[s];
  const int tid = threadIdx.x;
  const float* drow = dco + (size_t)s*2048;

  float mn = 3.4e38f, mx = -3.4e38f;
  for (int j = tid; j < 2048; j += 256) {
    float d = drow[j];
    mn = fminf(mn, d); mx = fmaxf(mx, d);
  }
  __shared__ float smn[256], smx[256];
  smn[tid] = mn; smx[tid] = mx;
  __syncthreads();
  for (int o = 128; o > 0; o >>= 1) {
    if (tid < o) { smn[tid] = fminf(smn[tid], smn[tid+o]); smx[tid] = fmaxf(smx[tid], smx[tid+o]); }
    __syncthreads();
  }
  const float dmin = smn[0], dmax = smx[0];
  const float margin = 0.06f*(dmax - dmin) + 1e-6f*fabsf(dmin) + 1e-20f;

  __shared__ int cand[64];
  __shared__ int cnt_s;
  if (tid == 0) cnt_s = 0;
  __syncthreads();
  for (int j = tid; j < 2048; j += 256) {
    if (drow[j] <= dmin + margin) {
      int p = atomicAdd(&cnt_s, 1);
      if (p < 64) cand[p] = j;
    }
  }
  __syncthreads();
  const int cnt = (cnt_s < 64) ? cnt_s : 64;

  __shared__ double red[256];
  __shared__ double bestd_s;
  __shared__ int bestc_s;
  if (tid == 0) { bestd_s = 1.0e300; bestc_s = 0x7fffffff; }
  __syncthreads();
  const float* zrow = zE + (size_t)s*4096;
  for (int t = 0; t < cnt; ++t) {
    const int gcode = cls*2048 + cand[t];
    const float* erow = E + (size_t)gcode*4096;
    double p = 0.0;
    for (int e2 = tid; e2 < 4096; e2 += 256) {
      double ev = (double)erow[e2];
      double zv = (double)zrow[e2];
      p += ev*ev - 2.0*zv*ev;
    }
    red[tid] = p;
    __syncthreads();
    for (int o = 128; o > 0; o >>= 1) {
      if (tid < o) red[tid] += red[tid+o];
      __syncthreads();
    }
    if (tid == 0) {
      double d = red[0];
      if (d < bestd_s || (d == bestd_s && gcode < bestc_s)) { bestd_s = d; bestc_s = gcode; }
    }
    __syncthreads();
  }
  if (tid == 0) codes[s] = bestc_s;
}

// gather + upsample<4,4>: zq fp32 out, zqt bf16 ch-last, u0t bf16 8x8 bilinear
__global__ __launch_bounds__(256) void gather_up_kernel(
    const int* __restrict__ codes, const int* __restrict__ perm,
    const float* __restrict__ E, float* __restrict__ zq,
    unsigned short* __restrict__ zqt, unsigned short* __restrict__ u0t)
{
  const int i = blockIdx.x;
  const int s = perm[i];
  const int code = codes[s];
  __shared__ unsigned short s_z[16*256];   // [sp][ci] bf16, 8 KB
  const float4* src = (const float4*)(E + (size_t)code*4096);
  float4* dst = (float4*)(zq + (size_t)i*4096);
  for (int t = threadIdx.x; t < 1024; t += 256) {
    float4 v = src[t];
    dst[t] = v;
    int e0 = t*4;
    int ci = e0 >> 4, sp = e0 & 15;
    unsigned short* zp = zqt + ((size_t)i*16 + sp)*256 + ci;
    unsigned short h0 = f2bf(v.x), h1 = f2bf(v.y), h2 = f2bf(v.z), h3 = f2bf(v.w);
    zp[0]   = h0;  zp[256] = h1;  zp[512] = h2;  zp[768] = h3;
    s_z[(sp+0)*256 + ci] = h0;
    s_z[(sp+1)*256 + ci] = h1;
    s_z[(sp+2)*256 + ci] = h2;
    s_z[(sp+3)*256 + ci] = h3;
  }
  __syncthreads();
  // bilinear 4->8, align_corners: src = out*3/7
  for (int q = threadIdx.x; q < 2048; q += 256) {
    int cig = q & 31;
    int pos = q >> 5;
    int xo = pos & 7, yo = pos >> 3;
    float ys = (float)(yo*3) / 7.f;
    float xs = (float)(xo*3) / 7.f;
    int ya = (int)ys; int yb = (ya+1 < 4) ? ya+1 : 3;
    int xa = (int)xs; int xb = (xa+1 < 4) ? xa+1 : 3;
    float wy = ys - (float)ya, wx = xs - (float)xa;
    vbf8 vaa = *(const vbf8*)(s_z + (ya*4+xa)*256 + cig*8);
    vbf8 vab = *(const vbf8*)(s_z + (ya*4+xb)*256 + cig*8);
    vbf8 vba = *(const vbf8*)(s_z + (yb*4+xa)*256 + cig*8);
    vbf8 vbb = *(const vbf8*)(s_z + (yb*4+xb)*256 + cig*8);
    vbf8 o;
#pragma unroll
    for (int j = 0; j < 8; ++j) {
      float r0 = bf2f((unsigned short)vaa[j])*(1.f-wy) + bf2f((unsigned short)vba[j])*wy;
      float r1 = bf2f((unsigned short)vab[j])*(1.f-wy) + bf2f((unsigned short)vbb[j])*wy;
      o[j] = (short)f2bf(r0*(1.f-wx) + r1*wx);
    }
    *(vbf8*)(u0t + (((size_t)i*8 + yo)*8 + xo)*256 + cig*8) = o;
  }
}

// ============ driver ===========================================================
extern "C" void kernel_launch(void* const* d_in, const int* in_sizes, int n_in,
                              void* d_out, int out_size, void* d_ws, size_t ws_size,
                              hipStream_t stream) {
  const float* x   = (const float*)d_in[0];
  const float* We0 = (const float*)d_in[1];
  const float* be0 = (const float*)d_in[2];
  const float* We1 = (const float*)d_in[3];
  const float* be1 = (const float*)d_in[4];
  const float* We2 = (const float*)d_in[5];
  const float* be2 = (const float*)d_in[6];
  const float* E   = (const float*)d_in[7];
  const float* Wd0 = (const float*)d_in[8];
  const float* bd0 = (const float*)d_in[9];
  const float* Wd1 = (const float*)d_in[10];
  const float* bd1 = (const float*)d_in[11];
  const float* Wd2 = (const float*)d_in[12];
  const float* bd2 = (const float*)d_in[13];
  const float* Wo  = (const float*)d_in[14];
  const float* bo  = (const float*)d_in[15];
  const int*   c   = (const int*)d_in[16];

  float* out = (float*)d_out;
  float* z_e = out + (size_t)512*784;
  float* zq  = z_e + (size_t)512*4096;

  char* ws = (char*)d_ws;
  size_t off = 0;
  float* norms = (float*)(ws + off); off += 65536;
  int* codes = (int*)(ws + off); off += 2048;
  int* perm = (int*)(ws + off); off += 2048;
  int* offs = (int*)(ws + off); off += 256;
  float* dco = (float*)(ws + off); off += (size_t)512*2048*4;
  unsigned short* zqt = (unsigned short*)(ws + off); off += (size_t)512*16*256*2;
  unsigned short* Et = (unsigned short*)(ws + off); off += (size_t)512*16384*8*2;
  unsigned short* Wt0  = (unsigned short*)(ws + off); off += 1179648;
  unsigned short* Wt0l = (unsigned short*)(ws + off); off += 1179648;
  unsigned short* Wt1  = (unsigned short*)(ws + off); off += 1179648;
  unsigned short* Wt1l = (unsigned short*)(ws + off); off += 1179648;
  unsigned short* Wt2  = (unsigned short*)(ws + off); off += 1179648;
  unsigned short* Wt2l = (unsigned short*)(ws + off); off += 1179648;
  unsigned short* We1h = (unsigned short*)(ws + off); off += 1179648;
  unsigned short* We1l = (unsigned short*)(ws + off); off += 1179648;
  unsigned short* We2h = (unsigned short*)(ws + off); off += 1179648;
  unsigned short* We2l = (unsigned short*)(ws + off); off += 1179648;
  char* big = ws + off;
  size_t avail = (ws_size > off) ? ws_size - off : 0;

  int NB = 512;
  while (NB > 1 && (size_t)NB * 1350656ull > avail) NB >>= 1;
  const int nch = 512 / NB;

  size_t o = 0;
  unsigned short* h0h = (unsigned short*)(big + o); o += (size_t)NB*100352;
  unsigned short* h0l = (unsigned short*)(big + o); o += (size_t)NB*100352;
  unsigned short* h1h = (unsigned short*)(big + o); o += (size_t)NB*25088;
  unsigned short* h1l = (unsigned short*)(big + o); o += (size_t)NB*25088;
  unsigned short* u0t = (unsigned short*)(big + o); o += (size_t)NB*32768;
  unsigned short* a0t = (unsigned short*)(big + o); o += (size_t)NB*32768;
  unsigned short* u1t = (unsigned short*)(big + o); o += (size_t)NB*131072;
  unsigned short* a1t = (unsigned short*)(big + o); o += (size_t)NB*100352;
  unsigned short* u2t = (unsigned short*)(big + o); o += (size_t)NB*401408;
  unsigned short* a2t = (unsigned short*)(big + o); o += (size_t)NB*401408;

  // ---- weight prep (single fused launch) + codebook prep ----
  wprep5_kernel<<<dim3(CDIV(589824,256),5), 256, 0, stream>>>(
      Wd0, Wt0, Wt0l, Wd1, Wt1, Wt1l, Wd2, Wt2, Wt2l,
      We1, We1h, We1l, We2, We2h, We2l);
  eprep_kernel<<<256, 256, 0, stream>>>(E, Et, norms);

  // ---- encoder (bf16x3 split MFMA, 8-stage DBUF w/ pinned prefetch) ----
  for (int ch = 0; ch < nch; ++ch) {
    conv_e0_cl_kernel<<<NB, 256, 0, stream>>>(x + (size_t)ch*NB*784, We0, be0, h0h, h0l);
    convmfma_kernel<2,7,7,0,8,8, 14,14,1,1,1,1, 1,8><<<dim3(NB,1), 256, 0, stream>>>(
        h0h, h0l, (const vbf8*)We1h, (const vbf8*)We1l, be1, h1h, h1l, nullptr);
    convmfma_kernel<2,4,4,0,4,4, 7,7,1,0,1,2, 1,8><<<dim3(NB,1), 256, 0, stream>>>(
        h1h, h1l, (const vbf8*)We2h, (const vbf8*)We2l, be2, nullptr, nullptr,
        z_e + (size_t)ch*NB*4096);
  }
  // ---- VQ: coarse MFMA + exact rescore ----
  perm_kernel<<<1, 512, 0, stream>>>(c, perm, offs);
  vq_coarse_kernel<<<dim3(8,8,8), 256, 0, stream>>>(
      z_e, (const vbf8*)Et, norms, perm, offs, dco);
  vq_select_kernel<<<512, 256, 0, stream>>>(dco, c, z_e, E, codes);
  gather_up_kernel<<<512, 256, 0, stream>>>(codes, perm, E, zq, zqt, u0t);

  // ---- decoder (bf16 MFMA, channel-last, chunked) — R10 configs ----
  for (int ch = 0; ch < nch; ++ch) {
    convmfma_kernel<1,8,8,0,8,8, 8,8,1,1,0,0, 1,8><<<dim3(NB,1), 256, 0, stream>>>(
        u0t + (size_t)ch*NB*16384, nullptr, (const vbf8*)Wt0, nullptr, bd0, a0t, nullptr, nullptr);
    upsample_cl_kernel<8,8><<<CDIV(NB*8192,256), 256, 0, stream>>>(a0t, u1t, NB);
    convmfma_kernel<1,14,14,0,16,4, 16,16,0,1,0,0, 1,8><<<dim3(NB,4), 256, 0, stream>>>(
        u1t, nullptr, (const vbf8*)Wt1, nullptr, bd1, a1t, nullptr, nullptr);
    upsample_cl_kernel<14,14><<<CDIV(NB*25088,256), 256, 0, stream>>>(a1t, u2t, NB);
    // d2: WOP=28, CIG=8, 2-barrier path — R7-proven 540 µs config
    convmfma_kernel<1,28,28,0,28,4, 28,28,1,1,0,0, 0,8><<<dim3(NB,7), 256, 0, stream>>>(
        u2t, nullptr, (const vbf8*)Wt2, nullptr, bd2, a2t, nullptr, nullptr);
    conv_out_t_kernel<<<dim3(NB,4), 256, 0, stream>>>(a2t, Wo, bo, out + (size_t)ch*NB*784);
  }
}

// Round 14
// 1703.222 us; speedup vs baseline: 1.2568x; 1.0849x over previous
//
#include <hip/hip_runtime.h>
#include <hip/hip_bf16.h>
#include <cstdint>
#include <cstddef>

#define CDIV(a,b) (((a)+(b)-1)/(b))

typedef __attribute__((ext_vector_type(8))) short vbf8;
typedef __attribute__((ext_vector_type(4))) float vf4;

__device__ inline unsigned short f2bf(float f) {
  unsigned u = __float_as_uint(f);
  unsigned r = (u + 0x7fffu + ((u >> 16) & 1u)) >> 16;
  return (unsigned short)r;
}
__device__ inline float bf2f(unsigned short h) { return __uint_as_float(((unsigned)h) << 16); }

// ============ encoder conv0: 1->256, 28->14, s2 p1, relu, ch-last hi/lo ========
__global__ __launch_bounds__(256) void conv_e0_cl_kernel(
    const float* __restrict__ x, const float* __restrict__ W,
    const float* __restrict__ b, unsigned short* __restrict__ hi,
    unsigned short* __restrict__ lo)
{
  __shared__ float s_img[784];
  const int n = blockIdx.x;
  const int co = threadIdx.x;
  for (int i = threadIdx.x; i < 784; i += 256) s_img[i] = x[(size_t)n*784 + i];
  float w[9];
#pragma unroll
  for (int t = 0; t < 9; ++t) w[t] = W[co*9 + t];
  const float bb = b[co];
  __syncthreads();
  for (int p = 0; p < 196; ++p) {
    int y = p / 14, xo = p % 14;
    float a = bb;
#pragma unroll
    for (int t = 0; t < 9; ++t) {
      int yi = 2*y + t/3 - 1, xi = 2*xo + t%3 - 1;
      if (yi >= 0 && yi < 28 && xi >= 0 && xi < 28) a = fmaf(w[t], s_img[yi*28 + xi], a);
    }
    a = fmaxf(a, 0.f);
    unsigned short h = f2bf(a);
    size_t oidx = ((size_t)n*196 + p)*256 + co;
    hi[oidx] = h;
    lo[oidx] = f2bf(a - bf2f(h));
  }
}

// ============ weight prep: 5 weights in one launch (blockIdx.y selects) ========
__global__ __launch_bounds__(256) void wprep5_kernel(
    const float* __restrict__ Wa, unsigned short* __restrict__ Ha, unsigned short* __restrict__ La,
    const float* __restrict__ Wb, unsigned short* __restrict__ Hb, unsigned short* __restrict__ Lb,
    const float* __restrict__ Wc, unsigned short* __restrict__ Hc, unsigned short* __restrict__ Lc,
    const float* __restrict__ Wd, unsigned short* __restrict__ Hd, unsigned short* __restrict__ Ld,
    const float* __restrict__ We, unsigned short* __restrict__ He, unsigned short* __restrict__ Le)
{
  int idx = blockIdx.x*256 + threadIdx.x;
  if (idx >= 589824) return;
  const float* W; unsigned short* Wh; unsigned short* Wl;
  switch (blockIdx.y) {
    case 0: W = Wa; Wh = Ha; Wl = La; break;
    case 1: W = Wb; Wh = Hb; Wl = Lb; break;
    case 2: W = Wc; Wh = Hc; Wl = Lc; break;
    case 3: W = Wd; Wh = Hd; Wl = Ld; break;
    default: W = We; Wh = He; Wl = Le; break;
  }
  int j   = idx & 7;
  int co  = (idx >> 3) & 255;
  int cig = (idx >> 11) & 31;
  int t   = idx >> 16;
  int ci  = cig*8 + j;
  float w = W[((size_t)co*256 + ci)*9 + t];
  unsigned short h = f2bf(w);
  Wh[idx] = h;
  Wl[idx] = f2bf(w - bf2f(h));
}

// ============ shared MFMA inner block ==========================================
template<int NFM, int WS, int CIG>
__device__ __forceinline__ void mfma_block(
    const vbf8* __restrict__ sbuf, const vbf8* __restrict__ wsrc, int cc,
    const int (&abase)[NFM], vf4 (&acc)[NFM][4], int cobase, int l15, int lq)
{
  constexpr int NKK = CIG/4;
#pragma unroll
  for (int t = 0; t < 9; ++t) {
    const int dy = t/3, dx = t%3;
#pragma unroll
    for (int kk = 0; kk < NKK; ++kk) {
      vbf8 bfr[4];
      const int cig_g = cc*CIG + kk*4 + lq;
#pragma unroll
      for (int nf = 0; nf < 4; ++nf)
        bfr[nf] = wsrc[((size_t)t*32 + cig_g)*256 + cobase + nf*16 + l15];
      vbf8 af[NFM];
      const int cigl = kk*4 + lq;
#pragma unroll
      for (int mf = 0; mf < NFM; ++mf) {
        int lin = abase[mf] + dy*WS + dx;
        af[mf] = sbuf[(lin*CIG + cigl) ^ (lin & 7)];
      }
#pragma unroll
      for (int mf = 0; mf < NFM; ++mf)
#pragma unroll
        for (int nf = 0; nf < 4; ++nf)
          acc[mf][nf] = __builtin_amdgcn_mfma_f32_16x16x32_bf16(af[mf], bfr[nf], acc[mf][nf], 0, 0, 0);
    }
  }
}

// ============ unified bf16 MFMA 3x3 conv, channel-last =========================
template<int STRIDE, int HO, int WO, int X0, int WOP, int ROWS, int HI, int WI,
         int PAD, int ACT, int SPLIT, int OUTMODE, int DBUF, int CIG>
__global__ __launch_bounds__(256, 2) void convmfma_kernel(
    const unsigned short* __restrict__ inT, const unsigned short* __restrict__ inTlo,
    const vbf8* __restrict__ Wt, const vbf8* __restrict__ Wtlo,
    const float* __restrict__ bias,
    unsigned short* __restrict__ outT, unsigned short* __restrict__ outTlo,
    float* __restrict__ outF)
{
  constexpr int NFM = ROWS*WOP/16;
  constexpr int RIN = (ROWS-1)*STRIDE + 3;
  constexpr int WS  = (WOP-1)*STRIDE + 3;
  constexpr int NCC = 256/(CIG*8);
  constexpr int NG  = SPLIT ? 3*NCC : NCC;
  constexpr int NELEM = RIN*WS*CIG;
  constexpr int CEIL = (NELEM + 255) / 256;
  __shared__ vbf8 sA[DBUF ? 2 : 1][NELEM];

  const int n  = blockIdx.x;
  const int y0 = blockIdx.y * ROWS;
  const int tid = threadIdx.x;
  const int lane = tid & 63;
  const int wv = tid >> 6;
  const int l15 = lane & 15;
  const int lq  = lane >> 4;
  const int cobase = wv * 64;

  int abase[NFM];
#pragma unroll
  for (int mf = 0; mf < NFM; ++mf) {
    int pos = mf*16 + l15;
    abase[mf] = (pos / WOP) * STRIDE * WS + (pos % WOP) * STRIDE;
  }

  vf4 acc[NFM][4];
#pragma unroll
  for (int mf = 0; mf < NFM; ++mf)
#pragma unroll
    for (int nf = 0; nf < 4; ++nf) acc[mf][nf] = (vf4){0.f, 0.f, 0.f, 0.f};

  if constexpr (DBUF) {
    int goff[CEIL];
#pragma unroll
    for (int q = 0; q < CEIL; ++q) {
      int idx = tid + q*256;
      int lin = idx / CIG, cig = idx % CIG;
      int rr = lin / WS, xx = lin % WS;
      int yi = y0*STRIDE + rr - PAD, xi = X0*STRIDE + xx - PAD;
      bool ok = (idx < NELEM) && yi >= 0 && yi < HI && xi >= 0 && xi < WI;
      goff[q] = ok ? (int)((((size_t)n*HI + yi)*WI + xi)*256 + cig*8) : -1;
    }
    vbf8 r[CEIL];
    // prologue: group 0 (pass 0, cc 0 -> hi plane, offset 0)
#pragma unroll
    for (int q = 0; q < CEIL; ++q) {
      vbf8 v = {0,0,0,0,0,0,0,0};
      if (goff[q] >= 0) v = *(const vbf8*)(inT + goff[q]);
      r[q] = v;
    }
#pragma unroll
    for (int q = 0; q < CEIL; ++q) {
      int idx = tid + q*256;
      if (idx < NELEM) { int lin = idx / CIG, cig = idx % CIG; sA[0][(lin*CIG + cig) ^ (lin & 7)] = r[q]; }
    }
    __syncthreads();
#pragma unroll 1
    for (int g = 0; g < NG; ++g) {
      if (g + 1 < NG) {
        const int passn = (g+1) / NCC;
        const unsigned short* srcn = (SPLIT && passn == 2) ? inTlo : inT;
        const int ccn = ((g+1) % NCC) * (CIG*8);
#pragma unroll
        for (int q = 0; q < CEIL; ++q) {
          vbf8 v = {0,0,0,0,0,0,0,0};
          if (goff[q] >= 0) v = *(const vbf8*)(srcn + goff[q] + ccn);
          r[q] = v;
        }
      }
      const int pass = g / NCC;
      const vbf8* wsrc = (SPLIT && pass == 1) ? Wtlo : Wt;
      mfma_block<NFM, WS, CIG>(sA[g & 1], wsrc, g % NCC, abase, acc, cobase, l15, lq);
      if (g + 1 < NG) {
        vbf8* nb = sA[(g+1) & 1];
#pragma unroll
        for (int q = 0; q < CEIL; ++q) {
          int idx = tid + q*256;
          if (idx < NELEM) { int lin = idx / CIG, cig = idx % CIG; nb[(lin*CIG + cig) ^ (lin & 7)] = r[q]; }
        }
      }
      __syncthreads();
    }
  } else {
    // 2-barrier path: stage -> sync -> MFMA -> sync
#pragma unroll 1
    for (int g = 0; g < NG; ++g) {
      const int pass = g / NCC;
      const int cc = g % NCC;
      const unsigned short* src = (SPLIT && pass == 2) ? inTlo : inT;
      const vbf8* wsrc = (SPLIT && pass == 1) ? Wtlo : Wt;
      for (int idx = tid; idx < NELEM; idx += 256) {
        int lin = idx / CIG, cig = idx % CIG;
        int rr = lin / WS, xx = lin % WS;
        int yi = y0*STRIDE + rr - PAD, xi = X0*STRIDE + xx - PAD;
        vbf8 v = {0,0,0,0,0,0,0,0};
        if (yi >= 0 && yi < HI && xi >= 0 && xi < WI)
          v = *(const vbf8*)(src + ((((size_t)n*HI + yi)*WI + xi)*256 + cc*(CIG*8) + cig*8));
        sA[0][(lin*CIG + cig) ^ (lin & 7)] = v;
      }
      __syncthreads();
      mfma_block<NFM, WS, CIG>(sA[0], wsrc, cc, abase, acc, cobase, l15, lq);
      __syncthreads();
    }
  }

  float bb[4];
#pragma unroll
  for (int nf = 0; nf < 4; ++nf) bb[nf] = bias[cobase + nf*16 + l15];
#pragma unroll
  for (int mf = 0; mf < NFM; ++mf) {
#pragma unroll
    for (int q = 0; q < 4; ++q) {
      int pos = mf*16 + lq*4 + q;
      int y = y0 + pos/WOP, x = X0 + pos % WOP;
      if (X0 + WOP > WO && x >= WO) continue;
      if (HO % ROWS != 0 && y >= HO) continue;
#pragma unroll
      for (int nf = 0; nf < 4; ++nf) {
        float v = acc[mf][nf][q] + bb[nf];
        if (ACT) v = fmaxf(v, 0.f);
        const int co = cobase + nf*16 + l15;
        if (OUTMODE == 2) {
          outF[((size_t)n*256 + co)*(HO*WO) + y*WO + x] = v;
        } else {
          size_t oidx = (((size_t)n*HO + y)*WO + x)*256 + co;
          unsigned short h = f2bf(v);
          outT[oidx] = h;
          if (OUTMODE == 1) outTlo[oidx] = f2bf(v - bf2f(h));
        }
      }
    }
  }
}

// ============ bilinear x2 upsample, channel-last bf16 ==========================
template<int H, int W>
__global__ __launch_bounds__(256) void upsample_cl_kernel(
    const unsigned short* __restrict__ in, unsigned short* __restrict__ out, int nimg)
{
  constexpr int Ho = 2*H, Wo = 2*W;
  int idx = blockIdx.x*256 + threadIdx.x;
  int total = nimg * Ho * Wo * 32;
  if (idx >= total) return;
  int cig = idx & 31; int rest = idx >> 5;
  int xo = rest % Wo; rest /= Wo;
  int yo = rest % Ho; int n = rest / Ho;
  float ys = (float)(yo*(H-1)) / (float)(Ho-1);
  float xs = (float)(xo*(W-1)) / (float)(Wo-1);
  int ya = (int)ys; int yb = (ya+1 < H) ? ya+1 : H-1;
  int xa = (int)xs; int xb = (xa+1 < W) ? xa+1 : W-1;
  float wy = ys - (float)ya, wx = xs - (float)xa;
  const unsigned short* base = in + (size_t)n*H*W*256 + cig*8;
  vbf8 vaa = *(const vbf8*)(base + ((size_t)ya*W + xa)*256);
  vbf8 vab = *(const vbf8*)(base + ((size_t)ya*W + xb)*256);
  vbf8 vba = *(const vbf8*)(base + ((size_t)yb*W + xa)*256);
  vbf8 vbb = *(const vbf8*)(base + ((size_t)yb*W + xb)*256);
  vbf8 o;
#pragma unroll
  for (int j = 0; j < 8; ++j) {
    float r0 = bf2f((unsigned short)vaa[j])*(1.f-wy) + bf2f((unsigned short)vba[j])*wy;
    float r1 = bf2f((unsigned short)vab[j])*(1.f-wy) + bf2f((unsigned short)vbb[j])*wy;
    o[j] = (short)f2bf(r0*(1.f-wx) + r1*wx);
  }
  *(vbf8*)(out + (((size_t)n*Ho + yo)*Wo + xo)*256 + cig*8) = o;
}

// ============ output conv: 256->1, 3x3 pad1, sigmoid (channel-last) ============
__global__ __launch_bounds__(256) void conv_out_t_kernel(
    const unsigned short* __restrict__ a2t, const float* __restrict__ Wo,
    const float* __restrict__ bo, float* __restrict__ out)
{
  const int n = blockIdx.x;
  const int y0 = blockIdx.y * 7;
  const int tid = threadIdx.x;
  __shared__ vbf8 s_in[9*30*8];
  __shared__ float s_w[9*64];
  const int p = tid;
  const int y = p / 28, x = p % 28;
  float acc = 0.f;
  for (int cc = 0; cc < 4; ++cc) {
    for (int idx = tid; idx < 9*30*8; idx += 256) {
      int lin = idx >> 3, cig = idx & 7;
      int r = lin / 30, xx = lin % 30;
      int yi = y0 + r - 1, xi = xx - 1;
      vbf8 v = {0,0,0,0,0,0,0,0};
      if (yi >= 0 && yi < 28 && xi >= 0 && xi < 28)
        v = *(const vbf8*)(a2t + (((size_t)n*28 + yi)*28 + xi)*256 + cc*64 + cig*8);
      s_in[(lin*8 + cig) ^ (lin & 7)] = v;
    }
    for (int idx = tid; idx < 576; idx += 256) {
      int t = idx / 64, cil = idx % 64;
      s_w[t*64 + cil] = Wo[((size_t)cc*64 + cil)*9 + t];
    }
    __syncthreads();
    if (p < 196) {
      float a = acc;
#pragma unroll
      for (int t = 0; t < 9; ++t) {
        int lin = (y + t/3)*30 + (x + t%3);
#pragma unroll
        for (int cig = 0; cig < 8; ++cig) {
          vbf8 v = s_in[(lin*8 + cig) ^ (lin & 7)];
#pragma unroll
          for (int j = 0; j < 8; ++j)
            a = fmaf(bf2f((unsigned short)v[j]), s_w[t*64 + cig*8 + j], a);
        }
      }
      acc = a;
    }
    __syncthreads();
  }
  if (p < 196)
    out[(size_t)n*784 + (y0 + y)*28 + x] = 1.f/(1.f + expf(-(acc + bo[0])));
}

// ============ VQ: E prep — one pass: Et bf16 transpose + fp32 norms ============
__global__ __launch_bounds__(256) void eprep_kernel(
    const float* __restrict__ E, unsigned short* __restrict__ Et,
    float* __restrict__ norms)
{
  const int cb = blockIdx.x;          // 256 blocks
  const int tid = threadIdx.x;
  const int cl = tid >> 2;
  const int seg = tid & 3;
  const int code = cb*64 + cl;
  const float4* srcRow = (const float4*)(E + (size_t)code*4096);
  vbf8* dst = (vbf8*)Et;
  float nacc = 0.f;
#pragma unroll 4
  for (int g8 = 0; g8 < 128; ++g8) {
    const int kg = g8*4 + seg;        // vbf8-group index, 0..511
    float4 a = srcRow[kg*2], b = srcRow[kg*2 + 1];
    nacc += a.x*a.x + a.y*a.y + a.z*a.z + a.w*a.w
          + b.x*b.x + b.y*b.y + b.z*b.z + b.w*b.w;
    vbf8 v;
    v[0]=(short)f2bf(a.x); v[1]=(short)f2bf(a.y); v[2]=(short)f2bf(a.z); v[3]=(short)f2bf(a.w);
    v[4]=(short)f2bf(b.x); v[5]=(short)f2bf(b.y); v[6]=(short)f2bf(b.z); v[7]=(short)f2bf(b.w);
    dst[(size_t)kg*16384 + code] = v;
  }
  nacc += __shfl_xor(nacc, 1);
  nacc += __shfl_xor(nacc, 2);
  if (seg == 0) norms[code] = nacc;
}

// ============ VQ: stable counting-sort permutation by class ====================
__global__ __launch_bounds__(512) void perm_kernel(
    const int* __restrict__ c, int* __restrict__ perm, int* __restrict__ off)
{
  __shared__ int sc[512];
  __shared__ int cnt[8];
  __shared__ int base[9];
  const int i = threadIdx.x;
  sc[i] = c[i];
  if (i < 8) cnt[i] = 0;
  __syncthreads();
  atomicAdd(&cnt[sc[i]], 1);
  __syncthreads();
  if (i == 0) { int a = 0; for (int j = 0; j < 8; ++j) { base[j] = a; a += cnt[j]; } base[8] = a; }
  __syncthreads();
  const int ci = sc[i];
  int rank = 0;
  for (int j = 0; j < i; ++j) rank += (sc[j] == ci) ? 1 : 0;
  perm[base[ci] + rank] = i;
  if (i < 9) off[i] = base[i];
}

// ============ VQ: coarse bf16 MFMA distance GEMM ===============================
__global__ __launch_bounds__(256) void vq_coarse_kernel(
    const float* __restrict__ zE, const vbf8* __restrict__ Etv,
    const float* __restrict__ norms, const int* __restrict__ perm,
    const int* __restrict__ offs, float* __restrict__ dco)
{
  const int cls = blockIdx.x;
  const int mb  = blockIdx.y;
  const int kb  = blockIdx.z;
  const int s0 = offs[cls];
  const int total = offs[cls+1] - s0;
  int nrows = total - mb*64;
  if (nrows <= 0) return;
  if (nrows > 64) nrows = 64;

  __shared__ vbf8 sA[64*8];
  __shared__ int srow_s[64];
  const int tid = threadIdx.x;
  if (tid < 64) srow_s[tid] = (tid < nrows) ? perm[s0 + mb*64 + tid] : -1;
  __syncthreads();

  const int lane = tid & 63;
  const int wv = tid >> 6;
  const int l15 = lane & 15;
  const int lq  = lane >> 4;

  const int myrow = tid >> 2;
  const int seg = tid & 3;
  const int srow_mine = srow_s[myrow];
  const float* zbase = (srow_mine >= 0) ? (zE + (size_t)srow_mine*4096 + seg*16) : nullptr;

  const int cbase = cls*2048 + kb*256 + wv*64;

  vf4 acc[4][4];
#pragma unroll
  for (int mf = 0; mf < 4; ++mf)
#pragma unroll
    for (int nf = 0; nf < 4; ++nf) acc[mf][nf] = (vf4){0.f, 0.f, 0.f, 0.f};

#pragma unroll 1
  for (int k0 = 0; k0 < 4096; k0 += 64) {
    {
      float4 v0, v1, v2, v3;
      if (zbase) {
        const float4* p = (const float4*)(zbase + k0);
        v0 = p[0]; v1 = p[1]; v2 = p[2]; v3 = p[3];
      } else {
        v0 = v1 = v2 = v3 = (float4){0.f, 0.f, 0.f, 0.f};
      }
      vbf8 a, b;
      a[0]=(short)f2bf(v0.x); a[1]=(short)f2bf(v0.y); a[2]=(short)f2bf(v0.z); a[3]=(short)f2bf(v0.w);
      a[4]=(short)f2bf(v1.x); a[5]=(short)f2bf(v1.y); a[6]=(short)f2bf(v1.z); a[7]=(short)f2bf(v1.w);
      b[0]=(short)f2bf(v2.x); b[1]=(short)f2bf(v2.y); b[2]=(short)f2bf(v2.z); b[3]=(short)f2bf(v2.w);
      b[4]=(short)f2bf(v3.x); b[5]=(short)f2bf(v3.y); b[6]=(short)f2bf(v3.z); b[7]=(short)f2bf(v3.w);
      int c0 = seg*2;
      sA[myrow*8 + (c0 ^ (myrow & 7))]       = a;
      sA[myrow*8 + ((c0 + 1) ^ (myrow & 7))] = b;
    }
    __syncthreads();
#pragma unroll
    for (int kb32 = 0; kb32 < 2; ++kb32) {
      vbf8 af[4], bf[4];
#pragma unroll
      for (int mf = 0; mf < 4; ++mf) {
        int row = mf*16 + l15;
        af[mf] = sA[row*8 + ((kb32*4 + lq) ^ (row & 7))];
      }
      const size_t kg = (size_t)((k0 >> 3) + kb32*4 + lq);
#pragma unroll
      for (int nf = 0; nf < 4; ++nf)
        bf[nf] = Etv[kg*16384 + cbase + nf*16 + l15];
#pragma unroll
      for (int mf = 0; mf < 4; ++mf)
#pragma unroll
        for (int nf = 0; nf < 4; ++nf)
          acc[mf][nf] = __builtin_amdgcn_mfma_f32_16x16x32_bf16(af[mf], bf[nf], acc[mf][nf], 0, 0, 0);
    }
    __syncthreads();
  }

  float nrm[4];
#pragma unroll
  for (int nf = 0; nf < 4; ++nf) nrm[nf] = norms[cbase + nf*16 + l15];
#pragma unroll
  for (int mf = 0; mf < 4; ++mf) {
#pragma unroll
    for (int q = 0; q < 4; ++q) {
      int slot = mf*16 + lq*4 + q;
      if (slot < nrows) {
        int s = srow_s[slot];
        float* drow = dco + (size_t)s*2048 + (kb*256 + wv*64);
#pragma unroll
        for (int nf = 0; nf < 4; ++nf)
          drow[nf*16 + l15] = nrm[nf] - 2.f*acc[mf][nf][q];
      }
    }
  }
}

// ============ VQ: candidate selection + exact fp64 rescore =====================
__global__ __launch_bounds__(256) void vq_select_kernel(
    const float* __restrict__ dco, const int* __restrict__ c,
    const float* __restrict__ zE, const float* __restrict__ E,
    int* __restrict__ codes)
{
  const int s = blockIdx.x;
  const int cls = c[s];
  const int tid = threadIdx.x;
  const float* drow = dco + (size_t)s*2048;

  float mn = 3.4e38f, mx = -3.4e38f;
  for (int j = tid; j < 2048; j += 256) {
    float d = drow[j];
    mn = fminf(mn, d); mx = fmaxf(mx, d);
  }
  __shared__ float smn[256], smx[256];
  smn[tid] = mn; smx[tid] = mx;
  __syncthreads();
  for (int o = 128; o > 0; o >>= 1) {
    if (tid < o) { smn[tid] = fminf(smn[tid], smn[tid+o]); smx[tid] = fmaxf(smx[tid], smx[tid+o]); }
    __syncthreads();
  }
  const float dmin = smn[0], dmax = smx[0];
  const float margin = 0.06f*(dmax - dmin) + 1e-6f*fabsf(dmin) + 1e-20f;

  __shared__ int cand[64];
  __shared__ int cnt_s;
  if (tid == 0) cnt_s = 0;
  __syncthreads();
  for (int j = tid; j < 2048; j += 256) {
    if (drow[j] <= dmin + margin) {
      int p = atomicAdd(&cnt_s, 1);
      if (p < 64) cand[p] = j;
    }
  }
  __syncthreads();
  const int cnt = (cnt_s < 64) ? cnt_s : 64;

  __shared__ double red[256];
  __shared__ double bestd_s;
  __shared__ int bestc_s;
  if (tid == 0) { bestd_s = 1.0e300; bestc_s = 0x7fffffff; }
  __syncthreads();
  const float* zrow = zE + (size_t)s*4096;
  for (int t = 0; t < cnt; ++t) {
    const int gcode = cls*2048 + cand[t];
    const float* erow = E + (size_t)gcode*4096;
    double p = 0.0;
    for (int e2 = tid; e2 < 4096; e2 += 256) {
      double ev = (double)erow[e2];
      double zv = (double)zrow[e2];
      p += ev*ev - 2.0*zv*ev;
    }
    red[tid] = p;
    __syncthreads();
    for (int o = 128; o > 0; o >>= 1) {
      if (tid < o) red[tid] += red[tid+o];
      __syncthreads();
    }
    if (tid == 0) {
      double d = red[0];
      if (d < bestd_s || (d == bestd_s && gcode < bestc_s)) { bestd_s = d; bestc_s = gcode; }
    }
    __syncthreads();
  }
  if (tid == 0) codes[s] = bestc_s;
}

// gather + upsample<4,4>: zq fp32 out, zqt bf16 ch-last, u0t bf16 8x8 bilinear
__global__ __launch_bounds__(256) void gather_up_kernel(
    const int* __restrict__ codes, const int* __restrict__ perm,
    const float* __restrict__ E, float* __restrict__ zq,
    unsigned short* __restrict__ zqt, unsigned short* __restrict__ u0t)
{
  const int i = blockIdx.x;
  const int s = perm[i];
  const int code = codes[s];
  __shared__ unsigned short s_z[16*256];   // [sp][ci] bf16, 8 KB
  const float4* src = (const float4*)(E + (size_t)code*4096);
  float4* dst = (float4*)(zq + (size_t)i*4096);
  for (int t = threadIdx.x; t < 1024; t += 256) {
    float4 v = src[t];
    dst[t] = v;
    int e0 = t*4;
    int ci = e0 >> 4, sp = e0 & 15;
    unsigned short* zp = zqt + ((size_t)i*16 + sp)*256 + ci;
    unsigned short h0 = f2bf(v.x), h1 = f2bf(v.y), h2 = f2bf(v.z), h3 = f2bf(v.w);
    zp[0]   = h0;  zp[256] = h1;  zp[512] = h2;  zp[768] = h3;
    s_z[(sp+0)*256 + ci] = h0;
    s_z[(sp+1)*256 + ci] = h1;
    s_z[(sp+2)*256 + ci] = h2;
    s_z[(sp+3)*256 + ci] = h3;
  }
  __syncthreads();
  // bilinear 4->8, align_corners: src = out*3/7
  for (int q = threadIdx.x; q < 2048; q += 256) {
    int cig = q & 31;
    int pos = q >> 5;
    int xo = pos & 7, yo = pos >> 3;
    float ys = (float)(yo*3) / 7.f;
    float xs = (float)(xo*3) / 7.f;
    int ya = (int)ys; int yb = (ya+1 < 4) ? ya+1 : 3;
    int xa = (int)xs; int xb = (xa+1 < 4) ? xa+1 : 3;
    float wy = ys - (float)ya, wx = xs - (float)xa;
    vbf8 vaa = *(const vbf8*)(s_z + (ya*4+xa)*256 + cig*8);
    vbf8 vab = *(const vbf8*)(s_z + (ya*4+xb)*256 + cig*8);
    vbf8 vba = *(const vbf8*)(s_z + (yb*4+xa)*256 + cig*8);
    vbf8 vbb = *(const vbf8*)(s_z + (yb*4+xb)*256 + cig*8);
    vbf8 o;
#pragma unroll
    for (int j = 0; j < 8; ++j) {
      float r0 = bf2f((unsigned short)vaa[j])*(1.f-wy) + bf2f((unsigned short)vba[j])*wy;
      float r1 = bf2f((unsigned short)vab[j])*(1.f-wy) + bf2f((unsigned short)vbb[j])*wy;
      o[j] = (short)f2bf(r0*(1.f-wx) + r1*wx);
    }
    *(vbf8*)(u0t + (((size_t)i*8 + yo)*8 + xo)*256 + cig*8) = o;
  }
}

// ============ driver ===========================================================
extern "C" void kernel_launch(void* const* d_in, const int* in_sizes, int n_in,
                              void* d_out, int out_size, void* d_ws, size_t ws_size,
                              hipStream_t stream) {
  const float* x   = (const float*)d_in[0];
  const float* We0 = (const float*)d_in[1];
  const float* be0 = (const float*)d_in[2];
  const float* We1 = (const float*)d_in[3];
  const float* be1 = (const float*)d_in[4];
  const float* We2 = (const float*)d_in[5];
  const float* be2 = (const float*)d_in[6];
  const float* E   = (const float*)d_in[7];
  const float* Wd0 = (const float*)d_in[8];
  const float* bd0 = (const float*)d_in[9];
  const float* Wd1 = (const float*)d_in[10];
  const float* bd1 = (const float*)d_in[11];
  const float* Wd2 = (const float*)d_in[12];
  const float* bd2 = (const float*)d_in[13];
  const float* Wo  = (const float*)d_in[14];
  const float* bo  = (const float*)d_in[15];
  const int*   c   = (const int*)d_in[16];

  float* out = (float*)d_out;
  float* z_e = out + (size_t)512*784;
  float* zq  = z_e + (size_t)512*4096;

  char* ws = (char*)d_ws;
  size_t off = 0;
  float* norms = (float*)(ws + off); off += 65536;
  int* codes = (int*)(ws + off); off += 2048;
  int* perm = (int*)(ws + off); off += 2048;
  int* offs = (int*)(ws + off); off += 256;
  float* dco = (float*)(ws + off); off += (size_t)512*2048*4;
  unsigned short* zqt = (unsigned short*)(ws + off); off += (size_t)512*16*256*2;
  unsigned short* Et = (unsigned short*)(ws + off); off += (size_t)512*16384*8*2;
  unsigned short* Wt0  = (unsigned short*)(ws + off); off += 1179648;
  unsigned short* Wt0l = (unsigned short*)(ws + off); off += 1179648;
  unsigned short* Wt1  = (unsigned short*)(ws + off); off += 1179648;
  unsigned short* Wt1l = (unsigned short*)(ws + off); off += 1179648;
  unsigned short* Wt2  = (unsigned short*)(ws + off); off += 1179648;
  unsigned short* Wt2l = (unsigned short*)(ws + off); off += 1179648;
  unsigned short* We1h = (unsigned short*)(ws + off); off += 1179648;
  unsigned short* We1l = (unsigned short*)(ws + off); off += 1179648;
  unsigned short* We2h = (unsigned short*)(ws + off); off += 1179648;
  unsigned short* We2l = (unsigned short*)(ws + off); off += 1179648;
  char* big = ws + off;
  size_t avail = (ws_size > off) ? ws_size - off : 0;

  int NB = 512;
  while (NB > 1 && (size_t)NB * 1350656ull > avail) NB >>= 1;
  const int nch = 512 / NB;

  size_t o = 0;
  unsigned short* h0h = (unsigned short*)(big + o); o += (size_t)NB*100352;
  unsigned short* h0l = (unsigned short*)(big + o); o += (size_t)NB*100352;
  unsigned short* h1h = (unsigned short*)(big + o); o += (size_t)NB*25088;
  unsigned short* h1l = (unsigned short*)(big + o); o += (size_t)NB*25088;
  unsigned short* u0t = (unsigned short*)(big + o); o += (size_t)NB*32768;
  unsigned short* a0t = (unsigned short*)(big + o); o += (size_t)NB*32768;
  unsigned short* u1t = (unsigned short*)(big + o); o += (size_t)NB*131072;
  unsigned short* a1t = (unsigned short*)(big + o); o += (size_t)NB*100352;
  unsigned short* u2t = (unsigned short*)(big + o); o += (size_t)NB*401408;
  unsigned short* a2t = (unsigned short*)(big + o); o += (size_t)NB*401408;

  // ---- weight prep (single fused launch) + codebook prep ----
  wprep5_kernel<<<dim3(CDIV(589824,256),5), 256, 0, stream>>>(
      Wd0, Wt0, Wt0l, Wd1, Wt1, Wt1l, Wd2, Wt2, Wt2l,
      We1, We1h, We1l, We2, We2h, We2l);
  eprep_kernel<<<256, 256, 0, stream>>>(E, Et, norms);

  // ---- encoder (bf16x3 split MFMA, chunked) ----
  for (int ch = 0; ch < nch; ++ch) {
    conv_e0_cl_kernel<<<NB, 256, 0, stream>>>(x + (size_t)ch*NB*784, We0, be0, h0h, h0l);
    // e1: ROWS=8, single y-block, DBUF, CIG=8
    convmfma_kernel<2,7,7,0,8,8, 14,14,1,1,1,1, 1,8><<<dim3(NB,1), 256, 0, stream>>>(
        h0h, h0l, (const vbf8*)We1h, (const vbf8*)We1l, be1, h1h, h1l, nullptr);
    convmfma_kernel<2,4,4,0,4,4, 7,7,1,0,1,2, 1,8><<<dim3(NB,1), 256, 0, stream>>>(
        h1h, h1l, (const vbf8*)We2h, (const vbf8*)We2l, be2, nullptr, nullptr,
        z_e + (size_t)ch*NB*4096);
  }
  // ---- VQ: coarse MFMA + exact rescore ----
  perm_kernel<<<1, 512, 0, stream>>>(c, perm, offs);
  vq_coarse_kernel<<<dim3(8,8,8), 256, 0, stream>>>(
      z_e, (const vbf8*)Et, norms, perm, offs, dco);
  vq_select_kernel<<<512, 256, 0, stream>>>(dco, c, z_e, E, codes);
  gather_up_kernel<<<512, 256, 0, stream>>>(codes, perm, E, zq, zqt, u0t);

  // ---- decoder (bf16 MFMA, channel-last, chunked) ----
  for (int ch = 0; ch < nch; ++ch) {
    convmfma_kernel<1,8,8,0,8,8, 8,8,1,1,0,0, 1,8><<<dim3(NB,1), 256, 0, stream>>>(
        u0t + (size_t)ch*NB*16384, nullptr, (const vbf8*)Wt0, nullptr, bd0, a0t, nullptr, nullptr);
    upsample_cl_kernel<8,8><<<CDIV(NB*8192,256), 256, 0, stream>>>(a0t, u1t, NB);
    convmfma_kernel<1,14,14,0,16,4, 16,16,0,1,0,0, 1,8><<<dim3(NB,4), 256, 0, stream>>>(
        u1t, nullptr, (const vbf8*)Wt1, nullptr, bd1, a1t, nullptr, nullptr);
    upsample_cl_kernel<14,14><<<CDIV(NB*25088,256), 256, 0, stream>>>(a1t, u2t, NB);
    // d2: WOP=28, CIG=8, 2-barrier path — proven 540 µs config
    convmfma_kernel<1,28,28,0,28,4, 28,28,1,1,0,0, 0,8><<<dim3(NB,7), 256, 0, stream>>>(
        u2t, nullptr, (const vbf8*)Wt2, nullptr, bd2, a2t, nullptr, nullptr);
    conv_out_t_kernel<<<dim3(NB,4), 256, 0, stream>>>(a2t, Wo, bo, out + (size_t)ch*NB*784);
  }
}